// Round 1
// baseline (1418.144 us; speedup 1.0000x reference)
//
#include <hip/hip_runtime.h>
#include <cstddef>

#define BN 4
#define TT 2048
#define MM 16
#define KK 16
#define DD 128
#define PP 256
#define HO 384      // D+P conv output channels
#define XPDc 768    // conv input channels
#define WCOLS 896   // W_in columns
#define LN_EPSf 1e-5f
#define DT_BIASf 1e-4f

// ---------------------------------------------------------------------------
// Kernel 1a: fold conv through W_in:  Wc[tap][d][o] = sum_i W_in[d,i]*conv_w[o,i,tap]
// grid 768 (= 384 o * 2 tap), block 128 (= d)
// ---------------------------------------------------------------------------
__global__ __launch_bounds__(128) void wc_kernel(const float* __restrict__ W_in,
                                                 const float* __restrict__ conv_w,
                                                 float* __restrict__ Wc) {
    __shared__ float cw[XPDc];
    const int o = blockIdx.x >> 1, tap = blockIdx.x & 1, d = threadIdx.x;
    for (int i = d; i < XPDc; i += 128) cw[i] = conv_w[(o * XPDc + i) * 2 + tap];
    __syncthreads();
    const float* wr = W_in + d * WCOLS;
    float acc = 0.f;
    #pragma unroll 8
    for (int i = 0; i < XPDc; ++i) acc += wr[i] * cw[i];
    Wc[tap * (DD * HO) + d * HO + o] = acc;
}

// ---------------------------------------------------------------------------
// Kernel 1b: zn = LN(slots_mu); q = zn @ Wq   (batch-invariant). 1 block, 256 thr.
// ---------------------------------------------------------------------------
__global__ __launch_bounds__(256) void q_kernel(const float* __restrict__ slots_mu,
                                                const float* __restrict__ ln_z_g,
                                                const float* __restrict__ ln_z_b,
                                                const float* __restrict__ Wq,
                                                float* __restrict__ qg) {
    __shared__ float zn[KK][DD];
    const int tid = threadIdx.x;
    const int wv = tid >> 6, ln_ = tid & 63;
    #pragma unroll
    for (int r = 0; r < 4; ++r) {
        int m = wv * 4 + r;
        float a0 = slots_mu[m * DD + ln_], a1 = slots_mu[m * DD + ln_ + 64];
        float s = a0 + a1, ss = a0 * a0 + a1 * a1;
        #pragma unroll
        for (int off = 32; off; off >>= 1) {
            s += __shfl_xor(s, off);
            ss += __shfl_xor(ss, off);
        }
        float mu = s * (1.f / 128.f);
        float var = ss * (1.f / 128.f) - mu * mu;
        float rs = rsqrtf(var + LN_EPSf);
        zn[m][ln_]      = (a0 - mu) * rs * ln_z_g[ln_]      + ln_z_b[ln_];
        zn[m][ln_ + 64] = (a1 - mu) * rs * ln_z_g[ln_ + 64] + ln_z_b[ln_ + 64];
    }
    __syncthreads();
    for (int idx = tid; idx < KK * DD; idx += 256) {
        int k2 = idx >> 7, c = idx & 127;
        float a = 0.f;
        #pragma unroll 8
        for (int d = 0; d < DD; ++d) a += zn[k2][d] * Wq[d * DD + c];
        qg[idx] = a;
    }
}

// ---------------------------------------------------------------------------
// Kernel 2: mega-fused per (b,t): h(conv) -> LN -> k,v -> attn -> u,pe_r ->
//           decay,dBu + res.  grid B*T = 8192, block 512.
// ---------------------------------------------------------------------------
__global__ __launch_bounds__(512) void fused_kernel(
    const float* __restrict__ x,
    const float* __restrict__ Wc,      // [2][128][384]
    const float* __restrict__ conv_b,
    const float* __restrict__ W_in,
    const float* __restrict__ qg,      // [16][128]
    const float* __restrict__ ln_x_g,
    const float* __restrict__ ln_x_b,
    const float* __restrict__ Wk,
    const float* __restrict__ Wv,
    const float* __restrict__ Wo,
    const float* __restrict__ A_log,
    float* __restrict__ decayg,
    float* __restrict__ dBug,
    float* __restrict__ resg) {
    __shared__ float sxT[2][DD][MM];   // x^T tiles; later reused: sxT[0]->kT, sxT[1]->suT
    __shared__ float sh[MM][HO];       // h rows (xs | pe)
    __shared__ float xnT[DD][MM];      // LN(xs)^T
    __shared__ float sv[MM][DD];       // v rows
    __shared__ float sattn[KK * MM];   // attn
    float* kT  = &sxT[0][0][0];        // [128][16]
    float* suT = &sxT[1][0][0];        // [128][16]

    const int tid = threadIdx.x;
    const int b = blockIdx.x / TT;
    const int t = blockIdx.x % TT;
    const size_t rbase = (size_t)(b * TT + t) * (MM * DD);

    // ---- Phase A: load x[b,t] and x[b,t-1], transposed ----
    const float* xcur = x + rbase;
    for (int idx = tid; idx < MM * DD; idx += 512) {
        int m = idx >> 7, d = idx & 127;
        sxT[1][d][m] = xcur[idx];
        sxT[0][d][m] = (t > 0) ? xcur[idx - MM * DD] : 0.f;
    }
    __syncthreads();

    // ---- Phase B: h = x_prev@Wc0 + x_cur@Wc1 + cb  (threads 0..383),
    //               res = silu(x_cur @ W_in[:,768:]) (threads 384..511) ----
    if (tid < HO) {
        const int o = tid;
        float acc[MM];
        #pragma unroll
        for (int m = 0; m < MM; ++m) acc[m] = 0.f;
        const float* w0p = Wc + o;
        const float* w1p = Wc + DD * HO + o;
        for (int d = 0; d < DD; ++d) {
            float w0 = w0p[d * HO];
            float w1 = w1p[d * HO];
            const float4* a0 = (const float4*)&sxT[0][d][0];
            const float4* a1 = (const float4*)&sxT[1][d][0];
            #pragma unroll
            for (int q4 = 0; q4 < 4; ++q4) {
                float4 v0 = a0[q4], v1 = a1[q4];
                acc[q4 * 4 + 0] += v0.x * w0 + v1.x * w1;
                acc[q4 * 4 + 1] += v0.y * w0 + v1.y * w1;
                acc[q4 * 4 + 2] += v0.z * w0 + v1.z * w1;
                acc[q4 * 4 + 3] += v0.w * w0 + v1.w * w1;
            }
        }
        float cb = conv_b[o];
        #pragma unroll
        for (int m = 0; m < MM; ++m) sh[m][o] = acc[m] + cb;
    } else {
        const int j = tid - HO;
        float acc[MM];
        #pragma unroll
        for (int m = 0; m < MM; ++m) acc[m] = 0.f;
        const float* wp = W_in + XPDc + j;
        for (int d = 0; d < DD; ++d) {
            float w = wp[d * WCOLS];
            const float4* a1 = (const float4*)&sxT[1][d][0];
            #pragma unroll
            for (int q4 = 0; q4 < 4; ++q4) {
                float4 v1 = a1[q4];
                acc[q4 * 4 + 0] += v1.x * w;
                acc[q4 * 4 + 1] += v1.y * w;
                acc[q4 * 4 + 2] += v1.z * w;
                acc[q4 * 4 + 3] += v1.w * w;
            }
        }
        #pragma unroll
        for (int m = 0; m < MM; ++m) {
            float v = acc[m];
            resg[rbase + m * DD + j] = v / (1.f + expf(-v));  // silu
        }
    }
    __syncthreads();

    // ---- Phase C: LN over xs = sh[:, :128] -> xnT ----
    {
        const int wv = tid >> 6, ln_ = tid & 63;
        #pragma unroll
        for (int r = 0; r < 2; ++r) {
            int m = wv * 2 + r;
            float a0 = sh[m][ln_], a1 = sh[m][ln_ + 64];
            float s = a0 + a1, ss = a0 * a0 + a1 * a1;
            #pragma unroll
            for (int off = 32; off; off >>= 1) {
                s += __shfl_xor(s, off);
                ss += __shfl_xor(ss, off);
            }
            float mu = s * (1.f / 128.f);
            float var = ss * (1.f / 128.f) - mu * mu;
            float rs = rsqrtf(var + LN_EPSf);
            xnT[ln_][m]      = (a0 - mu) * rs * ln_x_g[ln_]      + ln_x_b[ln_];
            xnT[ln_ + 64][m] = (a1 - mu) * rs * ln_x_g[ln_ + 64] + ln_x_b[ln_ + 64];
        }
    }
    __syncthreads();

    // ---- Phase D: k = xn@Wk (->kT), v = xn@Wv (->sv rows). m split in halves ----
    {
        const int c = tid & 127, sel = tid >> 7;
        const int mat = sel & 1, mh = (sel >> 1) & 1;
        const float* Wm = mat ? Wv : Wk;
        float acc[8];
        #pragma unroll
        for (int i = 0; i < 8; ++i) acc[i] = 0.f;
        for (int d = 0; d < DD; ++d) {
            float w = Wm[d * DD + c];
            const float4* xa = (const float4*)&xnT[d][mh * 8];
            float4 v0 = xa[0], v1 = xa[1];
            acc[0] += v0.x * w; acc[1] += v0.y * w;
            acc[2] += v0.z * w; acc[3] += v0.w * w;
            acc[4] += v1.x * w; acc[5] += v1.y * w;
            acc[6] += v1.z * w; acc[7] += v1.w * w;
        }
        if (mat == 0) {
            #pragma unroll
            for (int i = 0; i < 8; ++i) kT[c * MM + mh * 8 + i] = acc[i];
        } else {
            #pragma unroll
            for (int i = 0; i < 8; ++i) sv[mh * 8 + i][c] = acc[i];
        }
    }
    __syncthreads();

    // ---- Phase E: scores + softmax over m -> sattn ----
    if (tid < 256) {
        const int k2 = tid >> 4, m = tid & 15;
        float s = 0.f;
        #pragma unroll 8
        for (int d = 0; d < DD; ++d) s += qg[k2 * DD + d] * kT[d * MM + m];
        s *= 0.08838834764831845f;  // 1/sqrt(128)
        float mx = s;
        #pragma unroll
        for (int off = 8; off; off >>= 1) mx = fmaxf(mx, __shfl_xor(mx, off));
        float p = expf(s - mx);
        float sum = p;
        #pragma unroll
        for (int off = 8; off; off >>= 1) sum += __shfl_xor(sum, off);
        sattn[k2 * MM + m] = p / sum;
    }
    __syncthreads();

    // ---- Phase F: u1 = attn @ v  -> suT ----
    for (int idx = tid; idx < KK * DD; idx += 512) {
        int k2 = idx >> 7, d = idx & 127;
        float a = 0.f;
        #pragma unroll
        for (int m = 0; m < MM; ++m) a += sattn[k2 * MM + m] * sv[m][d];
        suT[d * MM + k2] = a;
    }
    __syncthreads();

    // ---- Phase G+H: u = u1@Wo; pe_r = attn@pe; dt,decay,dBu; write out ----
    {
        const int dout = tid & 127, g = tid >> 7;  // g: 4 k2's each
        float u0 = 0.f, u1 = 0.f, u2 = 0.f, u3 = 0.f;
        for (int d = 0; d < DD; ++d) {
            float w = Wo[d * DD + dout];
            const float4 us = *(const float4*)&suT[d * MM + g * 4];
            u0 += us.x * w; u1 += us.y * w; u2 += us.z * w; u3 += us.w * w;
        }
        float uu[4] = {u0, u1, u2, u3};
        const float A = -expf(A_log[0]);
        #pragma unroll
        for (int r = 0; r < 4; ++r) {
            int k2 = g * 4 + r;
            float pd = 0.f, pb = 0.f;
            #pragma unroll
            for (int m = 0; m < MM; ++m) {
                float a = sattn[k2 * MM + m];
                pd += a * sh[m][DD + dout];        // pe_r[:, :128]
                pb += a * sh[m][DD + PP + dout];   // pe_r[:, 128:]
            }
            float dt = fmaxf(pd, 0.f) + log1pf(expf(-fabsf(pd))) + DT_BIASf;
            float dec = expf(dt * A);
            float dbu = dt * pb * uu[r];
            size_t o = rbase + (size_t)k2 * DD + dout;
            decayg[o] = dec;
            dBug[o]   = dbu;
        }
    }
}

// ---------------------------------------------------------------------------
// Kernel 3: sequential SSM scan over t, per (b,k,d); fused z_hat gate.
// grid 64 (= B*K), block 128 (= d)
// ---------------------------------------------------------------------------
__global__ __launch_bounds__(128) void scan_kernel(const float* __restrict__ decayg,
                                                   const float* __restrict__ dBug,
                                                   const float* __restrict__ resg,
                                                   const float* __restrict__ slots_mu,
                                                   float* __restrict__ out) {
    const int b = blockIdx.x >> 4, k2 = blockIdx.x & 15, d = threadIdx.x;
    float h = slots_mu[k2 * DD + d];
    const size_t base = (size_t)b * TT * KK * DD + (size_t)k2 * DD + d;
    const size_t NTOT = (size_t)BN * TT * KK * DD;
    #pragma unroll 8
    for (int t = 0; t < TT; ++t) {
        size_t idx = base + (size_t)t * (KK * DD);
        float de = decayg[idx];
        float db = dBug[idx];
        h = fmaf(de, h, db);
        out[idx] = h * resg[idx];   // z_hat
        out[NTOT + idx] = h;        // z_all
    }
}

// ---------------------------------------------------------------------------
extern "C" void kernel_launch(void* const* d_in, const int* in_sizes, int n_in,
                              void* d_out, int out_size, void* d_ws, size_t ws_size,
                              hipStream_t stream) {
    const float* x        = (const float*)d_in[0];
    const float* W_in     = (const float*)d_in[1];
    const float* conv_w   = (const float*)d_in[2];
    const float* conv_b   = (const float*)d_in[3];
    const float* slots_mu = (const float*)d_in[4];
    const float* A_log    = (const float*)d_in[5];
    const float* ln_x_g   = (const float*)d_in[6];
    const float* ln_x_b   = (const float*)d_in[7];
    const float* ln_z_g   = (const float*)d_in[8];
    const float* ln_z_b   = (const float*)d_in[9];
    const float* Wq       = (const float*)d_in[10];
    const float* Wk       = (const float*)d_in[11];
    const float* Wv       = (const float*)d_in[12];
    const float* Wo       = (const float*)d_in[13];
    float* out = (float*)d_out;

    float* ws = (float*)d_ws;
    const size_t NT = (size_t)BN * TT * KK * DD;  // 16,777,216
    float* Wcb   = ws;                 // 2*128*384 = 98304
    float* qg    = ws + 98304;         // 2048
    float* decay = ws + 100352;        // NT
    float* dBu   = decay + NT;         // NT
    float* resb  = dBu + NT;           // NT

    wc_kernel<<<dim3(HO * 2), dim3(128), 0, stream>>>(W_in, conv_w, Wcb);
    q_kernel<<<dim3(1), dim3(256), 0, stream>>>(slots_mu, ln_z_g, ln_z_b, Wq, qg);
    fused_kernel<<<dim3(BN * TT), dim3(512), 0, stream>>>(
        x, Wcb, conv_b, W_in, qg, ln_x_g, ln_x_b, Wk, Wv, Wo, A_log,
        decay, dBu, resb);
    scan_kernel<<<dim3(BN * KK), dim3(128), 0, stream>>>(decay, dBu, resb, slots_mu, out);
}

// Round 2
// 661.554 us; speedup vs baseline: 2.1437x; 2.1437x over previous
//
#include <hip/hip_runtime.h>
#include <cstddef>

#define BN 4
#define TT 2048
#define MM 16
#define KK 16
#define DD 128
#define HO 384
#define RTOT (BN*TT*MM)                 // 131072 rows (b,t,m)
#define NTOT ((size_t)BN*TT*KK*DD)      // 16777216
#define LN_EPSf 1e-5f
#define DT_BIASf 1e-4f
#define CHUNKS 64
#define CLEN 32

typedef __attribute__((ext_vector_type(8))) short short8v;   // 8 x bf16 bits
typedef __attribute__((ext_vector_type(4))) float f32x4;

static __device__ __forceinline__ unsigned short f2b(float f) {
    union { float f; unsigned u; } x; x.f = f;
    unsigned r = (x.u + 0x7fffu + ((x.u >> 16) & 1u)) >> 16;   // RNE
    return (unsigned short)r;
}

// ---------------------------------------------------------------------------
// P1a: WT[n][k] (bf16, [512][256]) = conv folded through W_in (k<256 taps) and
//      res-projection cols (n>=384). grid 512, block 256.
// ---------------------------------------------------------------------------
__global__ __launch_bounds__(256) void wfold_kernel(const float* __restrict__ W_in,
                                                    const float* __restrict__ conv_w,
                                                    unsigned short* __restrict__ WT) {
    const int n = blockIdx.x, tid = threadIdx.x;
    if (n < HO) {
        __shared__ float cw0[768], cw1[768];
        for (int i = tid; i < 768; i += 256) {
            cw0[i] = conv_w[(n * 768 + i) * 2 + 0];
            cw1[i] = conv_w[(n * 768 + i) * 2 + 1];
        }
        __syncthreads();
        const int k = tid, dd = k & 127;
        const float* cw = (k < 128) ? cw0 : cw1;   // k<128: x_prev tap; else x_cur tap
        const float* wr = W_in + (size_t)dd * 896;
        float acc = 0.f;
        #pragma unroll 8
        for (int i = 0; i < 768; ++i) acc += wr[i] * cw[i];
        WT[(size_t)n * 256 + k] = f2b(acc);
    } else {
        const int k = tid;
        float v = (k < 128) ? 0.f : W_in[(size_t)(k - 128) * 896 + 768 + (n - HO)];
        WT[(size_t)n * 256 + k] = f2b(v);
    }
}

// ---------------------------------------------------------------------------
// P1b: W3T ([144][128] bf16): rows 0..127 = Wvo^T (Wvo = Wv@Wo),
//      rows 128..143 = q' = LN_z(slots)@Wq@Wk^T * rsqrt(D). grid 144, block 128.
// ---------------------------------------------------------------------------
__global__ __launch_bounds__(128) void w3_kernel(const float* __restrict__ slots_mu,
                                                 const float* __restrict__ ln_z_g,
                                                 const float* __restrict__ ln_z_b,
                                                 const float* __restrict__ Wq,
                                                 const float* __restrict__ Wk,
                                                 const float* __restrict__ Wv,
                                                 const float* __restrict__ Wo,
                                                 unsigned short* __restrict__ W3T) {
    const int n = blockIdx.x, tid = threadIdx.x;
    if (n < 128) {
        __shared__ float wo[128];
        wo[tid] = Wo[(size_t)tid * 128 + n];
        __syncthreads();
        const float* wv = Wv + (size_t)tid * 128;
        float acc = 0.f;
        #pragma unroll 8
        for (int c = 0; c < 128; ++c) acc += wv[c] * wo[c];
        W3T[(size_t)n * 128 + tid] = f2b(acc);
    } else {
        const int k2 = n - 128;
        __shared__ float zn[128], qv[128];
        __shared__ float red[4];
        float v = slots_mu[(size_t)k2 * 128 + tid];
        float s = v, ss = v * v;
        #pragma unroll
        for (int o = 32; o; o >>= 1) { s += __shfl_xor(s, o); ss += __shfl_xor(ss, o); }
        if ((tid & 63) == 0) { red[(tid >> 6) * 2] = s; red[(tid >> 6) * 2 + 1] = ss; }
        __syncthreads();
        float S = red[0] + red[2], SS = red[1] + red[3];
        float mu = S * (1.f / 128.f), var = SS * (1.f / 128.f) - mu * mu;
        float rs = rsqrtf(var + LN_EPSf);
        zn[tid] = (v - mu) * rs * ln_z_g[tid] + ln_z_b[tid];
        __syncthreads();
        float a = 0.f;
        for (int dd2 = 0; dd2 < 128; ++dd2) a += zn[dd2] * Wq[(size_t)dd2 * 128 + tid];
        qv[tid] = a;
        __syncthreads();
        float qp = 0.f;
        for (int c = 0; c < 128; ++c) qp += qv[c] * Wk[(size_t)tid * 128 + c];
        W3T[(size_t)n * 128 + tid] = f2b(qp * 0.08838834764831845f);
    }
}

// ---------------------------------------------------------------------------
// P2: x (fp32) -> Xb (bf16). grid 4096, block 256, 4 x float4 per thread.
// ---------------------------------------------------------------------------
__global__ __launch_bounds__(256) void cvt_kernel(const float* __restrict__ x,
                                                  unsigned short* __restrict__ Xb) {
    const size_t t0 = (size_t)blockIdx.x * 256 + threadIdx.x;
    #pragma unroll
    for (int it = 0; it < 4; ++it) {
        size_t i = t0 + (size_t)it * 1048576;
        float4 v = ((const float4*)x)[i];
        union { unsigned short s[4]; unsigned long long ll; } o;
        o.s[0] = f2b(v.x); o.s[1] = f2b(v.y); o.s[2] = f2b(v.z); o.s[3] = f2b(v.w);
        ((unsigned long long*)Xb)[i] = o.ll;
    }
}

// ---------------------------------------------------------------------------
// GEMM1: [131072][256] (im2col of Xb) @ WT^T -> Hxs | Hpe | silu->resg.
// 128x128 tile, 4 waves, direct-global fragment loads, no LDS.
// grid 4096 (ct = bid&3, rt = bid>>2), block 256.
// ---------------------------------------------------------------------------
__global__ __launch_bounds__(256) void gemm1_kernel(const unsigned short* __restrict__ Xb,
                                                    const unsigned short* __restrict__ WT,
                                                    const float* __restrict__ conv_b,
                                                    float* __restrict__ Hxs,
                                                    float* __restrict__ Hpe,
                                                    float* __restrict__ resg) {
    const int bid = blockIdx.x;
    const int ct = bid & 3, rt = bid >> 2;
    const int tid = threadIdx.x;
    const int wv = tid >> 6, l = tid & 63;
    const int wr = wv >> 1, wc = wv & 1;
    const int rowbase = rt * 128 + wr * 64;
    const int colbase = ct * 128 + wc * 64;
    const int lr = l & 15, lk = (l >> 4) * 8;

    f32x4 acc[4][4];
    #pragma unroll
    for (int i = 0; i < 4; ++i)
        #pragma unroll
        for (int j = 0; j < 4; ++j) acc[i][j] = (f32x4)0.f;

    #pragma unroll
    for (int ks = 0; ks < 8; ++ks) {
        const bool prev = ks < 4;                       // k<128 -> x[t-1]
        const int kk = (prev ? ks * 32 : ks * 32 - 128) + lk;
        short8v a[4], b[4];
        #pragma unroll
        for (int mf = 0; mf < 4; ++mf) {
            int row = rowbase + mf * 16 + lr;
            bool ok = !prev || ((row & (TT * MM - 1)) >= MM);
            int srow = prev ? row - MM : row;
            const unsigned short* p = ok ? (Xb + (size_t)srow * DD + kk) : Xb;
            short8v v = *(const short8v*)p;
            a[mf] = ok ? v : (short8v)(short)0;
        }
        #pragma unroll
        for (int nf = 0; nf < 4; ++nf) {
            int n = colbase + nf * 16 + lr;
            b[nf] = *(const short8v*)(WT + (size_t)n * 256 + ks * 32 + lk);
        }
        #pragma unroll
        for (int mf = 0; mf < 4; ++mf)
            #pragma unroll
            for (int nf = 0; nf < 4; ++nf)
                acc[mf][nf] = __builtin_amdgcn_mfma_f32_16x16x32_bf16(a[mf], b[nf], acc[mf][nf], 0, 0, 0);
    }

    const int rsub = (l >> 4) * 4;
    #pragma unroll
    for (int mf = 0; mf < 4; ++mf) {
        #pragma unroll
        for (int nf = 0; nf < 4; ++nf) {
            const int col = colbase + nf * 16 + lr;
            const float cb = (ct < 3) ? conv_b[col] : 0.f;
            #pragma unroll
            for (int r = 0; r < 4; ++r) {
                const int row = rowbase + mf * 16 + rsub + r;
                float v = acc[mf][nf][r];
                if (ct == 0) {
                    Hxs[(size_t)row * DD + col] = v + cb;
                } else if (ct < 3) {
                    Hpe[(size_t)row * 256 + (col - 128)] = v + cb;
                } else {
                    resg[(size_t)row * DD + (col - 384)] = v / (1.f + expf(-v));
                }
            }
        }
    }
}

// ---------------------------------------------------------------------------
// P4: LN rows of Hxs -> xnB (bf16). 4 rows/block (1 wave each). grid 32768.
// ---------------------------------------------------------------------------
__global__ __launch_bounds__(256) void ln_kernel(const float* __restrict__ Hxs,
                                                 const float* __restrict__ g,
                                                 const float* __restrict__ bb,
                                                 unsigned short* __restrict__ xnB) {
    const int row = blockIdx.x * 4 + (threadIdx.x >> 6);
    const int l = threadIdx.x & 63;
    const float2 v = *(const float2*)(Hxs + (size_t)row * DD + l * 2);
    float s = v.x + v.y, ss = v.x * v.x + v.y * v.y;
    #pragma unroll
    for (int o = 32; o; o >>= 1) { s += __shfl_xor(s, o); ss += __shfl_xor(ss, o); }
    float mu = s * (1.f / 128.f), var = ss * (1.f / 128.f) - mu * mu;
    float rs = rsqrtf(var + LN_EPSf);
    float2 gg = *(const float2*)(g + l * 2);
    float2 bv = *(const float2*)(bb + l * 2);
    union { unsigned short s[2]; unsigned u; } o;
    o.s[0] = f2b((v.x - mu) * rs * gg.x + bv.x);
    o.s[1] = f2b((v.y - mu) * rs * gg.y + bv.y);
    *(unsigned*)(xnB + (size_t)row * DD + l * 2) = o.u;
}

// ---------------------------------------------------------------------------
// GEMM3: xnB [131072][128] @ W3T^T ([144][128]) -> SVo [131072][144]
// (cols 0..127 = vo, 128..143 = scores). grid 1024, block 256 (4 waves x 32 rows).
// ---------------------------------------------------------------------------
__global__ __launch_bounds__(256) void gemm3_kernel(const unsigned short* __restrict__ xnB,
                                                    const unsigned short* __restrict__ W3T,
                                                    float* __restrict__ SVo) {
    const int rt = blockIdx.x;
    const int tid = threadIdx.x;
    const int wv = tid >> 6, l = tid & 63;
    const int lr = l & 15, lk = (l >> 4) * 8;
    const int rowbase = rt * 128 + wv * 32;

    f32x4 acc[2][9];
    #pragma unroll
    for (int i = 0; i < 2; ++i)
        #pragma unroll
        for (int j = 0; j < 9; ++j) acc[i][j] = (f32x4)0.f;

    #pragma unroll
    for (int ks = 0; ks < 4; ++ks) {
        short8v a[2], b[9];
        #pragma unroll
        for (int mf = 0; mf < 2; ++mf) {
            int row = rowbase + mf * 16 + lr;
            a[mf] = *(const short8v*)(xnB + (size_t)row * DD + ks * 32 + lk);
        }
        #pragma unroll
        for (int nf = 0; nf < 9; ++nf) {
            b[nf] = *(const short8v*)(W3T + (size_t)(nf * 16 + lr) * DD + ks * 32 + lk);
        }
        #pragma unroll
        for (int mf = 0; mf < 2; ++mf)
            #pragma unroll
            for (int nf = 0; nf < 9; ++nf)
                acc[mf][nf] = __builtin_amdgcn_mfma_f32_16x16x32_bf16(a[mf], b[nf], acc[mf][nf], 0, 0, 0);
    }

    const int rsub = (l >> 4) * 4;
    #pragma unroll
    for (int mf = 0; mf < 2; ++mf)
        #pragma unroll
        for (int nf = 0; nf < 9; ++nf) {
            const int col = nf * 16 + lr;
            #pragma unroll
            for (int r = 0; r < 4; ++r) {
                const int row = rowbase + mf * 16 + rsub + r;
                SVo[(size_t)row * 144 + col] = acc[mf][nf][r];
            }
        }
}

// ---------------------------------------------------------------------------
// fused2: per (b,t): softmax over m, u = attn@vo, pe_r = attn@pe,
//         dt/decay/dBu -> d_out (as scratch). grid 8192, block 256.
// ---------------------------------------------------------------------------
__global__ __launch_bounds__(256) void fused2_kernel(const float* __restrict__ SVo,
                                                     const float* __restrict__ Hpe,
                                                     const float* __restrict__ A_log,
                                                     float* __restrict__ decayg,
                                                     float* __restrict__ dBug) {
    __shared__ float svo[16 * 144];
    __shared__ float spe[16 * 256];
    __shared__ float sattn[256];
    const int bt = blockIdx.x, tid = threadIdx.x;
    const float* srcv = SVo + (size_t)bt * 16 * 144;
    const float* srcp = Hpe + (size_t)bt * 16 * 256;
    for (int i = tid; i < 16 * 144; i += 256) svo[i] = srcv[i];
    for (int i = tid; i < 16 * 256; i += 256) spe[i] = srcp[i];
    __syncthreads();
    {
        const int k2 = tid >> 4, m = tid & 15;
        float s = svo[m * 144 + 128 + k2];
        float mx = s;
        #pragma unroll
        for (int o = 8; o; o >>= 1) mx = fmaxf(mx, __shfl_xor(mx, o));
        float p = expf(s - mx);
        float sum = p;
        #pragma unroll
        for (int o = 8; o; o >>= 1) sum += __shfl_xor(sum, o);
        sattn[k2 * 16 + m] = p / sum;
    }
    __syncthreads();
    const int d = tid & 127, g = tid >> 7;     // g=0: k2 0..7, g=1: k2 8..15
    float u[8], pd[8], pb[8];
    #pragma unroll
    for (int r = 0; r < 8; ++r) { u[r] = 0.f; pd[r] = 0.f; pb[r] = 0.f; }
    for (int m = 0; m < 16; ++m) {
        float v  = svo[m * 144 + d];
        float p0 = spe[m * 256 + d];
        float p1 = spe[m * 256 + 128 + d];
        #pragma unroll
        for (int r = 0; r < 8; ++r) {
            float a = sattn[(g * 8 + r) * 16 + m];
            u[r]  += a * v;
            pd[r] += a * p0;
            pb[r] += a * p1;
        }
    }
    const float A = -expf(A_log[0]);
    const size_t rbase = (size_t)bt * KK * DD;
    #pragma unroll
    for (int r = 0; r < 8; ++r) {
        int k2 = g * 8 + r;
        float xv = pd[r];
        float dt = fmaxf(xv, 0.f) + log1pf(expf(-fabsf(xv))) + DT_BIASf;
        float dec = expf(dt * A);
        float dbu = dt * pb[r] * u[r];
        size_t o = rbase + (size_t)k2 * DD + d;
        decayg[o] = dec;
        dBug[o]   = dbu;
    }
}

// ---------------------------------------------------------------------------
// scanA: per (b,k,chunk) local scan from 0 -> chunk aggregates P,S.
// grid 4096 (bk*64+c), block 128.
// ---------------------------------------------------------------------------
__global__ __launch_bounds__(128) void scanA_kernel(const float* decayg, const float* dBug,
                                                    float* __restrict__ Pc, float* __restrict__ Sc) {
    const int c = blockIdx.x & (CHUNKS - 1), bk = blockIdx.x >> 6;
    const int b = bk >> 4, k2 = bk & 15, d = threadIdx.x;
    const size_t base = (((size_t)b * TT + c * CLEN) * KK + k2) * DD + d;
    float P = 1.f, S = 0.f;
    #pragma unroll 4
    for (int j = 0; j < CLEN; ++j) {
        size_t idx = base + (size_t)j * (KK * DD);
        float de = decayg[idx], db = dBug[idx];
        P *= de;
        S = fmaf(de, S, db);
    }
    Pc[(size_t)blockIdx.x * DD + d] = P;
    Sc[(size_t)blockIdx.x * DD + d] = S;
}

// ---------------------------------------------------------------------------
// scanB: combine chunk aggregates -> per-chunk initial states. grid 64, block 128.
// ---------------------------------------------------------------------------
__global__ __launch_bounds__(128) void scanB_kernel(const float* __restrict__ Pc,
                                                    const float* __restrict__ Sc,
                                                    const float* __restrict__ slots_mu,
                                                    float* __restrict__ Hinit) {
    const int bk = blockIdx.x, k2 = bk & 15, d = threadIdx.x;
    float h = slots_mu[(size_t)k2 * DD + d];
    #pragma unroll 8
    for (int c = 0; c < CHUNKS; ++c) {
        size_t i = ((size_t)bk * CHUNKS + c) * DD + d;
        Hinit[i] = h;
        h = fmaf(Pc[i], h, Sc[i]);
    }
}

// ---------------------------------------------------------------------------
// scanC: redo local scan with correct init; write z_hat,z_all (overwriting the
// decay/dBu scratch that lives in d_out — read-before-write, same thread).
// grid 4096, block 128.
// ---------------------------------------------------------------------------
__global__ __launch_bounds__(128) void scanC_kernel(const float* decayg, const float* dBug,
                                                    const float* __restrict__ resg,
                                                    const float* __restrict__ Hinit,
                                                    float* outA, float* outB) {
    const int c = blockIdx.x & (CHUNKS - 1), bk = blockIdx.x >> 6;
    const int b = bk >> 4, k2 = bk & 15, d = threadIdx.x;
    const size_t base = (((size_t)b * TT + c * CLEN) * KK + k2) * DD + d;
    float h = Hinit[((size_t)bk * CHUNKS + c) * DD + d];
    #pragma unroll 4
    for (int j = 0; j < CLEN; ++j) {
        size_t idx = base + (size_t)j * (KK * DD);
        float de = decayg[idx], db = dBug[idx];
        h = fmaf(de, h, db);
        outA[idx] = h * resg[idx];
        outB[idx] = h;
    }
}

// ---------------------------------------------------------------------------
extern "C" void kernel_launch(void* const* d_in, const int* in_sizes, int n_in,
                              void* d_out, int out_size, void* d_ws, size_t ws_size,
                              hipStream_t stream) {
    const float* x        = (const float*)d_in[0];
    const float* W_in     = (const float*)d_in[1];
    const float* conv_w   = (const float*)d_in[2];
    const float* conv_b   = (const float*)d_in[3];
    const float* slots_mu = (const float*)d_in[4];
    const float* A_log    = (const float*)d_in[5];
    const float* ln_x_g   = (const float*)d_in[6];
    const float* ln_x_b   = (const float*)d_in[7];
    const float* ln_z_g   = (const float*)d_in[8];
    const float* ln_z_b   = (const float*)d_in[9];
    const float* Wq       = (const float*)d_in[10];
    const float* Wk       = (const float*)d_in[11];
    const float* Wv       = (const float*)d_in[12];
    const float* Wo       = (const float*)d_in[13];

    char* w = (char*)d_ws;
    auto give = [&](size_t bytes) -> char* {
        char* r = w; w += (bytes + 255) & ~(size_t)255; return r;
    };
    unsigned short* WT    = (unsigned short*)give((size_t)512 * 256 * 2);
    unsigned short* W3T   = (unsigned short*)give((size_t)144 * 128 * 2);
    unsigned short* Xb    = (unsigned short*)give((size_t)RTOT * 128 * 2);  // later reused as xnB
    float* Hxs   = (float*)give((size_t)RTOT * 128 * 4);
    float* Hpe   = (float*)give((size_t)RTOT * 256 * 4);
    float* resg  = (float*)give((size_t)RTOT * 128 * 4);
    float* SVo   = (float*)give((size_t)RTOT * 144 * 4);
    float* Pc    = (float*)give((size_t)4096 * 128 * 4);
    float* Sc    = (float*)give((size_t)4096 * 128 * 4);
    float* Hinit = (float*)give((size_t)64 * CHUNKS * 128 * 4);

    float* decayg = (float*)d_out;              // d_out as scratch for decay
    float* dBug   = ((float*)d_out) + NTOT;     // and dBu
    unsigned short* xnB = Xb;                    // Xb dead after gemm1

    wfold_kernel<<<dim3(512), dim3(256), 0, stream>>>(W_in, conv_w, WT);
    w3_kernel<<<dim3(144), dim3(128), 0, stream>>>(slots_mu, ln_z_g, ln_z_b, Wq, Wk, Wv, Wo, W3T);
    cvt_kernel<<<dim3(4096), dim3(256), 0, stream>>>(x, Xb);
    gemm1_kernel<<<dim3(4096), dim3(256), 0, stream>>>(Xb, WT, conv_b, Hxs, Hpe, resg);
    ln_kernel<<<dim3(32768), dim3(256), 0, stream>>>(Hxs, ln_x_g, ln_x_b, xnB);
    gemm3_kernel<<<dim3(1024), dim3(256), 0, stream>>>(xnB, W3T, SVo);
    fused2_kernel<<<dim3(BN * TT), dim3(256), 0, stream>>>(SVo, Hpe, A_log, decayg, dBug);
    scanA_kernel<<<dim3(4096), dim3(128), 0, stream>>>(decayg, dBug, Pc, Sc);
    scanB_kernel<<<dim3(64), dim3(128), 0, stream>>>(Pc, Sc, slots_mu, Hinit);
    scanC_kernel<<<dim3(4096), dim3(128), 0, stream>>>(decayg, dBug, resg, Hinit, decayg, dBug);
}

// Round 3
// 599.891 us; speedup vs baseline: 2.3640x; 1.1028x over previous
//
#include <hip/hip_runtime.h>
#include <cstddef>

#define BN 4
#define TT 2048
#define MM 16
#define KK 16
#define DD 128
#define HO 384
#define RTOT (BN*TT*MM)                 // 131072 rows (b,t,m)
#define NTOT ((size_t)BN*TT*KK*DD)      // 16777216
#define LN_EPSf 1e-5f
#define DT_BIASf 1e-4f
#define CHUNKS 64
#define CLEN 32

typedef __attribute__((ext_vector_type(8))) short short8v;   // 8 x bf16 bits
typedef __attribute__((ext_vector_type(4))) float f32x4;

static __device__ __forceinline__ unsigned short f2b(float f) {
    union { float f; unsigned u; } x; x.f = f;
    unsigned r = (x.u + 0x7fffu + ((x.u >> 16) & 1u)) >> 16;   // RNE
    return (unsigned short)r;
}
static __device__ __forceinline__ uint2 pack4(float a, float b, float c, float d) {
    uint2 r;
    r.x = (unsigned)f2b(a) | ((unsigned)f2b(b) << 16);
    r.y = (unsigned)f2b(c) | ((unsigned)f2b(d) << 16);
    return r;
}
static __device__ __forceinline__ float blo(unsigned u) {
    union { unsigned u; float f; } x; x.u = u << 16; return x.f;
}
static __device__ __forceinline__ float bhi(unsigned u) {
    union { unsigned u; float f; } x; x.u = u & 0xffff0000u; return x.f;
}

// ---------------------------------------------------------------------------
// P1a: WT[n][k] (bf16, [512][256]) = conv folded through W_in (n<384) and
//      res-projection cols (n>=384). grid 512, block 256.
// ---------------------------------------------------------------------------
__global__ __launch_bounds__(256) void wfold_kernel(const float* __restrict__ W_in,
                                                    const float* __restrict__ conv_w,
                                                    unsigned short* __restrict__ WT) {
    const int n = blockIdx.x, tid = threadIdx.x;
    if (n < HO) {
        __shared__ float cw0[768], cw1[768];
        for (int i = tid; i < 768; i += 256) {
            cw0[i] = conv_w[(n * 768 + i) * 2 + 0];
            cw1[i] = conv_w[(n * 768 + i) * 2 + 1];
        }
        __syncthreads();
        const int k = tid, dd = k & 127;
        const float* cw = (k < 128) ? cw0 : cw1;   // k<128: x_prev tap; else x_cur tap
        const float* wr = W_in + (size_t)dd * 896;
        float acc = 0.f;
        #pragma unroll 8
        for (int i = 0; i < 768; ++i) acc += wr[i] * cw[i];
        WT[(size_t)n * 256 + k] = f2b(acc);
    } else {
        const int k = tid;
        float v = (k < 128) ? 0.f : W_in[(size_t)(k - 128) * 896 + 768 + (n - HO)];
        WT[(size_t)n * 256 + k] = f2b(v);
    }
}

// ---------------------------------------------------------------------------
// P1b: W3T ([144][128] bf16): rows 0..127 = Wvo^T (Wvo = Wv@Wo),
//      rows 128..143 = q' = LN_z(slots)@Wq@Wk^T * rsqrt(D). grid 144, block 128.
// ---------------------------------------------------------------------------
__global__ __launch_bounds__(128) void w3_kernel(const float* __restrict__ slots_mu,
                                                 const float* __restrict__ ln_z_g,
                                                 const float* __restrict__ ln_z_b,
                                                 const float* __restrict__ Wq,
                                                 const float* __restrict__ Wk,
                                                 const float* __restrict__ Wv,
                                                 const float* __restrict__ Wo,
                                                 unsigned short* __restrict__ W3T) {
    const int n = blockIdx.x, tid = threadIdx.x;
    if (n < 128) {
        __shared__ float wo[128];
        wo[tid] = Wo[(size_t)tid * 128 + n];
        __syncthreads();
        const float* wv = Wv + (size_t)tid * 128;
        float acc = 0.f;
        #pragma unroll 8
        for (int c = 0; c < 128; ++c) acc += wv[c] * wo[c];
        W3T[(size_t)n * 128 + tid] = f2b(acc);
    } else {
        const int k2 = n - 128;
        __shared__ float zn[128], qv[128];
        __shared__ float red[4];
        float v = slots_mu[(size_t)k2 * 128 + tid];
        float s = v, ss = v * v;
        #pragma unroll
        for (int o = 32; o; o >>= 1) { s += __shfl_xor(s, o); ss += __shfl_xor(ss, o); }
        if ((tid & 63) == 0) { red[(tid >> 6) * 2] = s; red[(tid >> 6) * 2 + 1] = ss; }
        __syncthreads();
        float S = red[0] + red[2], SS = red[1] + red[3];
        float mu = S * (1.f / 128.f), var = SS * (1.f / 128.f) - mu * mu;
        float rs = rsqrtf(var + LN_EPSf);
        zn[tid] = (v - mu) * rs * ln_z_g[tid] + ln_z_b[tid];
        __syncthreads();
        float a = 0.f;
        for (int dd2 = 0; dd2 < 128; ++dd2) a += zn[dd2] * Wq[(size_t)dd2 * 128 + tid];
        qv[tid] = a;
        __syncthreads();
        float qp = 0.f;
        for (int c = 0; c < 128; ++c) qp += qv[c] * Wk[(size_t)tid * 128 + c];
        W3T[(size_t)n * 128 + tid] = f2b(qp * 0.08838834764831845f);
    }
}

// ---------------------------------------------------------------------------
// P2: x (fp32) -> Xb (bf16). grid 4096, block 256, 4 x float4 per thread.
// ---------------------------------------------------------------------------
__global__ __launch_bounds__(256) void cvt_kernel(const float* __restrict__ x,
                                                  unsigned short* __restrict__ Xb) {
    const size_t t0 = (size_t)blockIdx.x * 256 + threadIdx.x;
    #pragma unroll
    for (int it = 0; it < 4; ++it) {
        size_t i = t0 + (size_t)it * 1048576;
        float4 v = ((const float4*)x)[i];
        union { unsigned short s[4]; unsigned long long ll; } o;
        o.s[0] = f2b(v.x); o.s[1] = f2b(v.y); o.s[2] = f2b(v.z); o.s[3] = f2b(v.w);
        ((unsigned long long*)Xb)[i] = o.ll;
    }
}

// ---------------------------------------------------------------------------
// GEMM1: [131072][256] (im2col of Xb) @ WT^T, swapped-operand MFMA (acc = C^T
// layout: lane&15 = x-row, regs = 4 consecutive cols). Wave tile 32x128.
//  ct=0: +conv_b -> LN (shuffle over lane-groups) -> xnB bf16
//  ct=1,2: +conv_b -> Hpe bf16
//  ct=3: silu -> resg fp32
// grid 4096 (ct=bid&3, rt=bid>>2), block 256.
// ---------------------------------------------------------------------------
__global__ __launch_bounds__(256) void gemm1_kernel(const unsigned short* __restrict__ Xb,
                                                    const unsigned short* __restrict__ WT,
                                                    const float* __restrict__ conv_b,
                                                    const float* __restrict__ ln_x_g,
                                                    const float* __restrict__ ln_x_b,
                                                    unsigned short* __restrict__ xnB,
                                                    unsigned short* __restrict__ Hpe,
                                                    float* __restrict__ resg) {
    const int bid = blockIdx.x;
    const int ct = bid & 3, rt = bid >> 2;
    const int tid = threadIdx.x;
    const int wv = tid >> 6, l = tid & 63;
    const int lr = l & 15, g = l >> 4, lk = g * 8;
    const int rowbase = rt * 128 + wv * 32;
    const int colbase = ct * 128;

    f32x4 acc[2][8];
    #pragma unroll
    for (int i = 0; i < 2; ++i)
        #pragma unroll
        for (int j = 0; j < 8; ++j) acc[i][j] = (f32x4)0.f;

    #pragma unroll
    for (int ks = 0; ks < 8; ++ks) {
        const bool prev = ks < 4;                       // k<128 -> x[t-1]
        const int kk = (prev ? ks * 32 : ks * 32 - 128) + lk;
        short8v a[2];
        #pragma unroll
        for (int mf = 0; mf < 2; ++mf) {
            int row = rowbase + mf * 16 + lr;
            bool ok = !prev || ((row & (TT * MM - 1)) >= MM);
            int srow = prev ? row - MM : row;
            const unsigned short* p = ok ? (Xb + (size_t)srow * DD + kk) : Xb;
            short8v v = *(const short8v*)p;
            a[mf] = ok ? v : (short8v)(short)0;
        }
        short8v b[8];
        #pragma unroll
        for (int nf = 0; nf < 8; ++nf)
            b[nf] = *(const short8v*)(WT + (size_t)(colbase + nf * 16 + lr) * 256 + ks * 32 + lk);
        #pragma unroll
        for (int mf = 0; mf < 2; ++mf)
            #pragma unroll
            for (int nf = 0; nf < 8; ++nf)
                acc[mf][nf] = __builtin_amdgcn_mfma_f32_16x16x32_bf16(b[nf], a[mf], acc[mf][nf], 0, 0, 0);
    }
    // lane holds: row = rowbase + mf*16 + lr; cols = colbase + nf*16 + g*4 + r

    if (ct == 0) {
        // +conv_b, LN over the 128 cols (spread across 4 lane-groups g), -> xnB bf16
        f32x4 cb[8];
        #pragma unroll
        for (int nf = 0; nf < 8; ++nf) cb[nf] = *(const f32x4*)(conv_b + nf * 16 + g * 4);
        #pragma unroll
        for (int mf = 0; mf < 2; ++mf) {
            float s = 0.f, ss = 0.f;
            #pragma unroll
            for (int nf = 0; nf < 8; ++nf)
                #pragma unroll
                for (int r = 0; r < 4; ++r) {
                    float v = acc[mf][nf][r] + cb[nf][r];
                    acc[mf][nf][r] = v;
                    s += v; ss += v * v;
                }
            s += __shfl_xor(s, 16);  s += __shfl_xor(s, 32);
            ss += __shfl_xor(ss, 16); ss += __shfl_xor(ss, 32);
            float mu = s * (1.f / 128.f);
            float var = ss * (1.f / 128.f) - mu * mu;
            float rs = rsqrtf(var + LN_EPSf);
            const int row = rowbase + mf * 16 + lr;
            #pragma unroll
            for (int nf = 0; nf < 8; ++nf) {
                f32x4 gv = *(const f32x4*)(ln_x_g + nf * 16 + g * 4);
                f32x4 bv = *(const f32x4*)(ln_x_b + nf * 16 + g * 4);
                float o0 = (acc[mf][nf][0] - mu) * rs * gv[0] + bv[0];
                float o1 = (acc[mf][nf][1] - mu) * rs * gv[1] + bv[1];
                float o2 = (acc[mf][nf][2] - mu) * rs * gv[2] + bv[2];
                float o3 = (acc[mf][nf][3] - mu) * rs * gv[3] + bv[3];
                *(uint2*)(xnB + (size_t)row * DD + nf * 16 + g * 4) = pack4(o0, o1, o2, o3);
            }
        }
    } else if (ct < 3) {
        #pragma unroll
        for (int mf = 0; mf < 2; ++mf) {
            const int row = rowbase + mf * 16 + lr;
            #pragma unroll
            for (int nf = 0; nf < 8; ++nf) {
                const int col = colbase + nf * 16 + g * 4;
                f32x4 cb = *(const f32x4*)(conv_b + col);
                *(uint2*)(Hpe + (size_t)row * 256 + (col - 128)) =
                    pack4(acc[mf][nf][0] + cb[0], acc[mf][nf][1] + cb[1],
                          acc[mf][nf][2] + cb[2], acc[mf][nf][3] + cb[3]);
            }
        }
    } else {
        #pragma unroll
        for (int mf = 0; mf < 2; ++mf) {
            const int row = rowbase + mf * 16 + lr;
            #pragma unroll
            for (int nf = 0; nf < 8; ++nf) {
                f32x4 o;
                #pragma unroll
                for (int r = 0; r < 4; ++r) {
                    float v = acc[mf][nf][r];
                    o[r] = v / (1.f + expf(-v));
                }
                *(f32x4*)(resg + (size_t)row * DD + nf * 16 + g * 4) = o;
            }
        }
    }
}

// ---------------------------------------------------------------------------
// GEMM3F: merged gemm3 + fused2. Wave = one (b,t): 16 rows.
//  GEMM: xn[16][128] @ W3T^T -> vo[16][128] + scores[16][16] (swapped layout)
//  softmax over m via lane shuffles; vo,attn through LDS; u/pd/pb contraction;
//  dt/decay/dBu -> d_out scratch. grid 2048, block 256 (4 waves).
// ---------------------------------------------------------------------------
__global__ __launch_bounds__(256) void gemm3f_kernel(const unsigned short* __restrict__ xnB,
                                                     const unsigned short* __restrict__ W3T,
                                                     const unsigned short* __restrict__ Hpe,
                                                     const float* __restrict__ A_log,
                                                     float* __restrict__ decayg,
                                                     float* __restrict__ dBug) {
    __shared__ float sV[4][16 * 130 + 2];   // per-wave vo fp32, padded stride 130
    __shared__ float sA[4][256];            // per-wave attn[m][k2]
    const int tid = threadIdx.x, wv = tid >> 6, l = tid & 63;
    const int lr = l & 15, g = l >> 4, lk = g * 8;
    const int bt = blockIdx.x * 4 + wv;
    const int rb = bt * 16;

    f32x4 acc[9];
    #pragma unroll
    for (int j = 0; j < 9; ++j) acc[j] = (f32x4)0.f;

    #pragma unroll
    for (int ks = 0; ks < 4; ++ks) {
        short8v a = *(const short8v*)(xnB + (size_t)(rb + lr) * DD + ks * 32 + lk);
        #pragma unroll
        for (int nf = 0; nf < 9; ++nf) {
            short8v b = *(const short8v*)(W3T + (size_t)(nf * 16 + lr) * DD + ks * 32 + lk);
            acc[nf] = __builtin_amdgcn_mfma_f32_16x16x32_bf16(b, a, acc[nf], 0, 0, 0);
        }
    }
    // acc[nf<8][r]: vo[m=lr][d=nf*16+g*4+r];  acc[8][r]: scores[m=lr][k2=g*4+r]

    // softmax over m (lane bits 0..3) per k2
    #pragma unroll
    for (int r = 0; r < 4; ++r) {
        float sc = acc[8][r];
        float mx = sc;
        #pragma unroll
        for (int off = 1; off <= 8; off <<= 1) mx = fmaxf(mx, __shfl_xor(mx, off));
        float p = expf(sc - mx);
        float sm = p;
        #pragma unroll
        for (int off = 1; off <= 8; off <<= 1) sm += __shfl_xor(sm, off);
        sA[wv][lr * 16 + g * 4 + r] = p / sm;   // attn[m][k2]
    }
    // vo -> LDS (fp32, padded)
    #pragma unroll
    for (int nf = 0; nf < 8; ++nf) {
        float* dst = &sV[wv][lr * 130 + nf * 16 + g * 4];
        *(float2*)dst = make_float2(acc[nf][0], acc[nf][1]);
        *(float2*)(dst + 2) = make_float2(acc[nf][2], acc[nf][3]);
    }
    __syncthreads();

    // per-lane: d = 2l, 2l+1
    float vo0[16], vo1[16];
    unsigned pe0[16], pe1[16];
    #pragma unroll
    for (int m = 0; m < 16; ++m) {
        float2 t = *(const float2*)&sV[wv][m * 130 + 2 * l];
        vo0[m] = t.x; vo1[m] = t.y;
        pe0[m] = *(const unsigned*)(Hpe + (size_t)(rb + m) * 256 + 2 * l);
        pe1[m] = *(const unsigned*)(Hpe + (size_t)(rb + m) * 256 + 128 + 2 * l);
    }
    const float A = -expf(A_log[0]);
    for (int k2 = 0; k2 < 16; ++k2) {
        float u0 = 0.f, u1 = 0.f, pd0 = 0.f, pd1 = 0.f, pb0 = 0.f, pb1 = 0.f;
        #pragma unroll
        for (int m = 0; m < 16; ++m) {
            float a = sA[wv][m * 16 + k2];
            u0 += a * vo0[m];       u1 += a * vo1[m];
            pd0 += a * blo(pe0[m]); pd1 += a * bhi(pe0[m]);
            pb0 += a * blo(pe1[m]); pb1 += a * bhi(pe1[m]);
        }
        float dt0 = fmaxf(pd0, 0.f) + log1pf(expf(-fabsf(pd0))) + DT_BIASf;
        float dt1 = fmaxf(pd1, 0.f) + log1pf(expf(-fabsf(pd1))) + DT_BIASf;
        float de0 = expf(dt0 * A), de1 = expf(dt1 * A);
        float db0 = dt0 * pb0 * u0, db1 = dt1 * pb1 * u1;
        size_t o = ((size_t)bt * KK + k2) * DD + 2 * l;
        *(float2*)(decayg + o) = make_float2(de0, de1);
        *(float2*)(dBug + o)   = make_float2(db0, db1);
    }
}

// ---------------------------------------------------------------------------
// scanA: per (b,k,chunk) local scan from 0 -> chunk aggregates P,S.
// ---------------------------------------------------------------------------
__global__ __launch_bounds__(128) void scanA_kernel(const float* decayg, const float* dBug,
                                                    float* __restrict__ Pc, float* __restrict__ Sc) {
    const int c = blockIdx.x & (CHUNKS - 1), bk = blockIdx.x >> 6;
    const int b = bk >> 4, k2 = bk & 15, d = threadIdx.x;
    const size_t base = (((size_t)b * TT + c * CLEN) * KK + k2) * DD + d;
    float P = 1.f, S = 0.f;
    #pragma unroll 4
    for (int j = 0; j < CLEN; ++j) {
        size_t idx = base + (size_t)j * (KK * DD);
        float de = decayg[idx], db = dBug[idx];
        P *= de;
        S = fmaf(de, S, db);
    }
    Pc[(size_t)blockIdx.x * DD + d] = P;
    Sc[(size_t)blockIdx.x * DD + d] = S;
}

// ---------------------------------------------------------------------------
// scanB: combine chunk aggregates -> per-chunk initial states. grid 64.
// ---------------------------------------------------------------------------
__global__ __launch_bounds__(128) void scanB_kernel(const float* __restrict__ Pc,
                                                    const float* __restrict__ Sc,
                                                    const float* __restrict__ slots_mu,
                                                    float* __restrict__ Hinit) {
    const int bk = blockIdx.x, k2 = bk & 15, d = threadIdx.x;
    float h = slots_mu[(size_t)k2 * DD + d];
    #pragma unroll 8
    for (int c = 0; c < CHUNKS; ++c) {
        size_t i = ((size_t)bk * CHUNKS + c) * DD + d;
        Hinit[i] = h;
        h = fmaf(Pc[i], h, Sc[i]);
    }
}

// ---------------------------------------------------------------------------
// scanC: local scan with correct init; write z_hat,z_all (overwriting the
// decay/dBu scratch living in d_out — read-before-write, same thread).
// ---------------------------------------------------------------------------
__global__ __launch_bounds__(128) void scanC_kernel(const float* decayg, const float* dBug,
                                                    const float* __restrict__ resg,
                                                    const float* __restrict__ Hinit,
                                                    float* outA, float* outB) {
    const int c = blockIdx.x & (CHUNKS - 1), bk = blockIdx.x >> 6;
    const int b = bk >> 4, k2 = bk & 15, d = threadIdx.x;
    const size_t base = (((size_t)b * TT + c * CLEN) * KK + k2) * DD + d;
    float h = Hinit[((size_t)bk * CHUNKS + c) * DD + d];
    #pragma unroll 4
    for (int j = 0; j < CLEN; ++j) {
        size_t idx = base + (size_t)j * (KK * DD);
        float de = decayg[idx], db = dBug[idx];
        h = fmaf(de, h, db);
        outA[idx] = h * resg[idx];
        outB[idx] = h;
    }
}

// ---------------------------------------------------------------------------
extern "C" void kernel_launch(void* const* d_in, const int* in_sizes, int n_in,
                              void* d_out, int out_size, void* d_ws, size_t ws_size,
                              hipStream_t stream) {
    const float* x        = (const float*)d_in[0];
    const float* W_in     = (const float*)d_in[1];
    const float* conv_w   = (const float*)d_in[2];
    const float* conv_b   = (const float*)d_in[3];
    const float* slots_mu = (const float*)d_in[4];
    const float* A_log    = (const float*)d_in[5];
    const float* ln_x_g   = (const float*)d_in[6];
    const float* ln_x_b   = (const float*)d_in[7];
    const float* ln_z_g   = (const float*)d_in[8];
    const float* ln_z_b   = (const float*)d_in[9];
    const float* Wq       = (const float*)d_in[10];
    const float* Wk       = (const float*)d_in[11];
    const float* Wv       = (const float*)d_in[12];
    const float* Wo       = (const float*)d_in[13];

    char* w = (char*)d_ws;
    auto give = [&](size_t bytes) -> char* {
        char* r = w; w += (bytes + 255) & ~(size_t)255; return r;
    };
    unsigned short* WT  = (unsigned short*)give((size_t)512 * 256 * 2);
    unsigned short* W3T = (unsigned short*)give((size_t)144 * 128 * 2);
    unsigned short* Xb  = (unsigned short*)give((size_t)RTOT * 128 * 2);
    unsigned short* xnB = (unsigned short*)give((size_t)RTOT * 128 * 2);
    unsigned short* Hpe = (unsigned short*)give((size_t)RTOT * 256 * 2);
    float* resg  = (float*)give((size_t)RTOT * 128 * 4);
    float* Pc    = (float*)give((size_t)4096 * 128 * 4);
    float* Sc    = (float*)give((size_t)4096 * 128 * 4);
    float* Hinit = (float*)give((size_t)64 * CHUNKS * 128 * 4);

    float* decayg = (float*)d_out;              // d_out as scratch for decay
    float* dBug   = ((float*)d_out) + NTOT;     // and dBu

    wfold_kernel<<<dim3(512), dim3(256), 0, stream>>>(W_in, conv_w, WT);
    w3_kernel<<<dim3(144), dim3(128), 0, stream>>>(slots_mu, ln_z_g, ln_z_b, Wq, Wk, Wv, Wo, W3T);
    cvt_kernel<<<dim3(4096), dim3(256), 0, stream>>>(x, Xb);
    gemm1_kernel<<<dim3(4096), dim3(256), 0, stream>>>(Xb, WT, conv_b, ln_x_g, ln_x_b, xnB, Hpe, resg);
    gemm3f_kernel<<<dim3(2048), dim3(256), 0, stream>>>(xnB, W3T, Hpe, A_log, decayg, dBug);
    scanA_kernel<<<dim3(4096), dim3(128), 0, stream>>>(decayg, dBug, Pc, Sc);
    scanB_kernel<<<dim3(64), dim3(128), 0, stream>>>(Pc, Sc, slots_mu, Hinit);
    scanC_kernel<<<dim3(4096), dim3(128), 0, stream>>>(decayg, dBug, resg, Hinit, decayg, dBug);
}

// Round 4
// 503.096 us; speedup vs baseline: 2.8188x; 1.1924x over previous
//
#include <hip/hip_runtime.h>
#include <cstddef>

#define BN 4
#define TT 2048
#define MM 16
#define KK 16
#define DD 128
#define HO 384
#define RTOT (BN*TT*MM)                 // 131072 rows (b,t,m)
#define NTOT ((size_t)BN*TT*KK*DD)      // 16777216
#define LN_EPSf 1e-5f
#define DT_BIASf 1e-4f
#define CHUNKS 64
#define CLEN 32

typedef __attribute__((ext_vector_type(8))) short short8v;   // 8 x bf16 bits
typedef __attribute__((ext_vector_type(4))) float f32x4;

static __device__ __forceinline__ unsigned short f2b(float f) {
    union { float f; unsigned u; } x; x.f = f;
    unsigned r = (x.u + 0x7fffu + ((x.u >> 16) & 1u)) >> 16;   // RNE
    return (unsigned short)r;
}
static __device__ __forceinline__ uint2 pack4(float a, float b, float c, float d) {
    uint2 r;
    r.x = (unsigned)f2b(a) | ((unsigned)f2b(b) << 16);
    r.y = (unsigned)f2b(c) | ((unsigned)f2b(d) << 16);
    return r;
}
static __device__ __forceinline__ float blo(unsigned u) {
    union { unsigned u; float f; } x; x.u = u << 16; return x.f;
}
static __device__ __forceinline__ float bhi(unsigned u) {
    union { unsigned u; float f; } x; x.u = u & 0xffff0000u; return x.f;
}
static __device__ __forceinline__ void gl_lds16(const void* g, void* l) {
    __builtin_amdgcn_global_load_lds(
        (const __attribute__((address_space(1))) void*)g,
        (__attribute__((address_space(3))) void*)l, 16, 0, 0);
}

// ---------------------------------------------------------------------------
// P1a: WT[n][k] (bf16, [512][256]) = conv folded through W_in (n<384) and
//      res-projection cols (n>=384). grid 512, block 256.
// ---------------------------------------------------------------------------
__global__ __launch_bounds__(256) void wfold_kernel(const float* __restrict__ W_in,
                                                    const float* __restrict__ conv_w,
                                                    unsigned short* __restrict__ WT) {
    const int n = blockIdx.x, tid = threadIdx.x;
    if (n < HO) {
        __shared__ float cw0[768], cw1[768];
        for (int i = tid; i < 768; i += 256) {
            cw0[i] = conv_w[(n * 768 + i) * 2 + 0];
            cw1[i] = conv_w[(n * 768 + i) * 2 + 1];
        }
        __syncthreads();
        const int k = tid, dd = k & 127;
        const float* cw = (k < 128) ? cw0 : cw1;   // k<128: x_prev tap; else x_cur tap
        const float* wr = W_in + (size_t)dd * 896;
        float acc = 0.f;
        #pragma unroll 8
        for (int i = 0; i < 768; ++i) acc += wr[i] * cw[i];
        WT[(size_t)n * 256 + k] = f2b(acc);
    } else {
        const int k = tid;
        float v = (k < 128) ? 0.f : W_in[(size_t)(k - 128) * 896 + 768 + (n - HO)];
        WT[(size_t)n * 256 + k] = f2b(v);
    }
}

// ---------------------------------------------------------------------------
// P1b: W3T ([144][128] bf16): rows 0..127 = Wvo^T (Wvo = Wv@Wo),
//      rows 128..143 = q' = LN_z(slots)@Wq@Wk^T * rsqrt(D). grid 144, block 128.
// ---------------------------------------------------------------------------
__global__ __launch_bounds__(128) void w3_kernel(const float* __restrict__ slots_mu,
                                                 const float* __restrict__ ln_z_g,
                                                 const float* __restrict__ ln_z_b,
                                                 const float* __restrict__ Wq,
                                                 const float* __restrict__ Wk,
                                                 const float* __restrict__ Wv,
                                                 const float* __restrict__ Wo,
                                                 unsigned short* __restrict__ W3T) {
    const int n = blockIdx.x, tid = threadIdx.x;
    if (n < 128) {
        __shared__ float wo[128];
        wo[tid] = Wo[(size_t)tid * 128 + n];
        __syncthreads();
        const float* wv = Wv + (size_t)tid * 128;
        float acc = 0.f;
        #pragma unroll 8
        for (int c = 0; c < 128; ++c) acc += wv[c] * wo[c];
        W3T[(size_t)n * 128 + tid] = f2b(acc);
    } else {
        const int k2 = n - 128;
        __shared__ float zn[128], qv[128];
        __shared__ float red[4];
        float v = slots_mu[(size_t)k2 * 128 + tid];
        float s = v, ss = v * v;
        #pragma unroll
        for (int o = 32; o; o >>= 1) { s += __shfl_xor(s, o); ss += __shfl_xor(ss, o); }
        if ((tid & 63) == 0) { red[(tid >> 6) * 2] = s; red[(tid >> 6) * 2 + 1] = ss; }
        __syncthreads();
        float S = red[0] + red[2], SS = red[1] + red[3];
        float mu = S * (1.f / 128.f), var = SS * (1.f / 128.f) - mu * mu;
        float rs = rsqrtf(var + LN_EPSf);
        zn[tid] = (v - mu) * rs * ln_z_g[tid] + ln_z_b[tid];
        __syncthreads();
        float a = 0.f;
        for (int dd2 = 0; dd2 < 128; ++dd2) a += zn[dd2] * Wq[(size_t)dd2 * 128 + tid];
        qv[tid] = a;
        __syncthreads();
        float qp = 0.f;
        for (int c = 0; c < 128; ++c) qp += qv[c] * Wk[(size_t)tid * 128 + c];
        W3T[(size_t)n * 128 + tid] = f2b(qp * 0.08838834764831845f);
    }
}

// ---------------------------------------------------------------------------
// P2: x (fp32) -> Xb (bf16) + zero the 256-B zbuf. grid 4096, block 256.
// ---------------------------------------------------------------------------
__global__ __launch_bounds__(256) void cvt_kernel(const float* __restrict__ x,
                                                  unsigned short* __restrict__ Xb,
                                                  float* __restrict__ zbuf) {
    if (blockIdx.x == 0 && threadIdx.x < 64) zbuf[threadIdx.x] = 0.f;
    const size_t t0 = (size_t)blockIdx.x * 256 + threadIdx.x;
    #pragma unroll
    for (int it = 0; it < 4; ++it) {
        size_t i = t0 + (size_t)it * 1048576;
        float4 v = ((const float4*)x)[i];
        union { unsigned short s[4]; unsigned long long ll; } o;
        o.s[0] = f2b(v.x); o.s[1] = f2b(v.y); o.s[2] = f2b(v.z); o.s[3] = f2b(v.w);
        ((unsigned long long*)Xb)[i] = o.ll;
    }
}

// ---------------------------------------------------------------------------
// GEMM1 (m97-style): [131072][256] (im2col of Xb) @ WT^T.
// 128x128 tile, BK=64, LDS-staged via global_load_lds(16B), XOR-swizzled
// chunks (chunk ^= row&7) on BOTH stage-source and ds_read.
// Swapped-operand MFMA: lane&15 = x-row, regs = 4 consecutive cols.
// Wave tile 32x128 (wave wv owns rows wv*32..wv*32+31).
//  ct=0: +conv_b -> LN -> xnB bf16; ct=1,2: +conv_b -> Hpe bf16; ct=3: silu -> resg.
// grid 4096 (ct=bid&3, rt=bid>>2), block 256.
// ---------------------------------------------------------------------------
__global__ __launch_bounds__(256) void gemm1_kernel(const unsigned short* __restrict__ Xb,
                                                    const unsigned short* __restrict__ WT,
                                                    const float* __restrict__ zbuf,
                                                    const float* __restrict__ conv_b,
                                                    const float* __restrict__ ln_x_g,
                                                    const float* __restrict__ ln_x_b,
                                                    unsigned short* __restrict__ xnB,
                                                    unsigned short* __restrict__ Hpe,
                                                    float* __restrict__ resg) {
    __shared__ unsigned short Asm[128 * 64];   // 16 KB, [row][64k], swizzled 16B chunks
    __shared__ unsigned short Bsm[128 * 64];   // 16 KB, [n][64k], swizzled

    const int bid = blockIdx.x;
    const int ct = bid & 3, rt = bid >> 2;
    const int tid = threadIdx.x;
    const int wv = tid >> 6, l = tid & 63;
    const int lr = l & 15, g = l >> 4;
    const int rowbase = rt * 128;
    const int colbase = ct * 128;

    // staging geometry: lane l of wave-issue (wv,j) covers LDS bytes seg*1024 + l*16
    const int srow = (wv * 8) + (l >> 3);      // row within a 2-issue group... per-issue row
    const char* XbB = (const char*)Xb;
    const char* WTB = (const char*)WT;
    char* AsmB = (char*)Asm;
    char* BsmB = (char*)Bsm;

    f32x4 acc[2][8];
    #pragma unroll
    for (int i = 0; i < 2; ++i)
        #pragma unroll
        for (int j = 0; j < 8; ++j) acc[i][j] = (f32x4)0.f;

    const bool edge = (rt & 255) == 0;          // tile contains t=0 rows (0..15)

    #pragma unroll
    for (int ks = 0; ks < 4; ++ks) {
        // ---- stage A and B tiles (each wave: 4+4 issues of 1KB) ----
        #pragma unroll
        for (int j = 0; j < 4; ++j) {
            const int seg = wv * 4 + j;
            const int row = seg * 8 + (l >> 3);      // 0..127
            const int chunk = l & 7;
            const int gch = chunk ^ (row & 7);
            // A: im2col source
            {
                const int grow = rowbase + row + (ks < 2 ? -16 : 0);
                const bool ok = (ks >= 2) || !edge || (row >= 16);
                const char* src = ok ? (XbB + ((size_t)grow * 256 + (ks & 1) * 128 + gch * 16))
                                     : (const char*)zbuf;
                gl_lds16(src, AsmB + seg * 1024);
            }
            // B: WT slice
            {
                const int n = colbase + row;
                gl_lds16(WTB + ((size_t)n * 512 + ks * 128 + gch * 16), BsmB + seg * 1024);
            }
        }
        __syncthreads();   // compiler drains vmcnt before s_barrier

        // ---- compute: 2 kb x (2 a-frags + 8 b-frags + 16 MFMA) per wave ----
        #pragma unroll
        for (int kb = 0; kb < 2; ++kb) {
            short8v a[2], b[8];
            #pragma unroll
            for (int mf = 0; mf < 2; ++mf) {
                const int arow = wv * 32 + mf * 16 + lr;
                const int aoff = arow * 128 + (((kb * 4 + g) ^ (arow & 7)) * 16);
                a[mf] = *(const short8v*)(AsmB + aoff);
            }
            #pragma unroll
            for (int nf = 0; nf < 8; ++nf) {
                const int brow = nf * 16 + lr;
                const int boff = brow * 128 + (((kb * 4 + g) ^ (brow & 7)) * 16);
                b[nf] = *(const short8v*)(BsmB + boff);
            }
            #pragma unroll
            for (int mf = 0; mf < 2; ++mf)
                #pragma unroll
                for (int nf = 0; nf < 8; ++nf)
                    acc[mf][nf] = __builtin_amdgcn_mfma_f32_16x16x32_bf16(b[nf], a[mf], acc[mf][nf], 0, 0, 0);
        }
        __syncthreads();   // before next stage overwrites LDS
    }
    // lane holds: row = rowbase + wv*32 + mf*16 + lr; cols = colbase + nf*16 + g*4 + r

    if (ct == 0) {
        f32x4 cb[8];
        #pragma unroll
        for (int nf = 0; nf < 8; ++nf) cb[nf] = *(const f32x4*)(conv_b + nf * 16 + g * 4);
        #pragma unroll
        for (int mf = 0; mf < 2; ++mf) {
            float s = 0.f, ss = 0.f;
            #pragma unroll
            for (int nf = 0; nf < 8; ++nf)
                #pragma unroll
                for (int r = 0; r < 4; ++r) {
                    float v = acc[mf][nf][r] + cb[nf][r];
                    acc[mf][nf][r] = v;
                    s += v; ss += v * v;
                }
            s += __shfl_xor(s, 16);  s += __shfl_xor(s, 32);
            ss += __shfl_xor(ss, 16); ss += __shfl_xor(ss, 32);
            float mu = s * (1.f / 128.f);
            float var = ss * (1.f / 128.f) - mu * mu;
            float rs = rsqrtf(var + LN_EPSf);
            const int row = rowbase + wv * 32 + mf * 16 + lr;
            #pragma unroll
            for (int nf = 0; nf < 8; ++nf) {
                f32x4 gv = *(const f32x4*)(ln_x_g + nf * 16 + g * 4);
                f32x4 bv = *(const f32x4*)(ln_x_b + nf * 16 + g * 4);
                float o0 = (acc[mf][nf][0] - mu) * rs * gv[0] + bv[0];
                float o1 = (acc[mf][nf][1] - mu) * rs * gv[1] + bv[1];
                float o2 = (acc[mf][nf][2] - mu) * rs * gv[2] + bv[2];
                float o3 = (acc[mf][nf][3] - mu) * rs * gv[3] + bv[3];
                *(uint2*)(xnB + (size_t)row * DD + nf * 16 + g * 4) = pack4(o0, o1, o2, o3);
            }
        }
    } else if (ct < 3) {
        #pragma unroll
        for (int mf = 0; mf < 2; ++mf) {
            const int row = rowbase + wv * 32 + mf * 16 + lr;
            #pragma unroll
            for (int nf = 0; nf < 8; ++nf) {
                const int col = colbase + nf * 16 + g * 4;
                f32x4 cb = *(const f32x4*)(conv_b + col);
                *(uint2*)(Hpe + (size_t)row * 256 + (col - 128)) =
                    pack4(acc[mf][nf][0] + cb[0], acc[mf][nf][1] + cb[1],
                          acc[mf][nf][2] + cb[2], acc[mf][nf][3] + cb[3]);
            }
        }
    } else {
        #pragma unroll
        for (int mf = 0; mf < 2; ++mf) {
            const int row = rowbase + wv * 32 + mf * 16 + lr;
            #pragma unroll
            for (int nf = 0; nf < 8; ++nf) {
                f32x4 o;
                #pragma unroll
                for (int r = 0; r < 4; ++r) {
                    float v = acc[mf][nf][r];
                    o[r] = v / (1.f + expf(-v));
                }
                *(f32x4*)(resg + (size_t)row * DD + nf * 16 + g * 4) = o;
            }
        }
    }
}

// ---------------------------------------------------------------------------
// GEMM3F: merged gemm3 + fused2. Wave = one (b,t): 16 rows.
// ---------------------------------------------------------------------------
__global__ __launch_bounds__(256) void gemm3f_kernel(const unsigned short* __restrict__ xnB,
                                                     const unsigned short* __restrict__ W3T,
                                                     const unsigned short* __restrict__ Hpe,
                                                     const float* __restrict__ A_log,
                                                     float* __restrict__ decayg,
                                                     float* __restrict__ dBug) {
    __shared__ float sV[4][16 * 130 + 2];   // per-wave vo fp32, padded stride 130
    __shared__ float sA[4][256];            // per-wave attn[m][k2]
    const int tid = threadIdx.x, wv = tid >> 6, l = tid & 63;
    const int lr = l & 15, g = l >> 4, lk = g * 8;
    const int bt = blockIdx.x * 4 + wv;
    const int rb = bt * 16;

    f32x4 acc[9];
    #pragma unroll
    for (int j = 0; j < 9; ++j) acc[j] = (f32x4)0.f;

    #pragma unroll
    for (int ks = 0; ks < 4; ++ks) {
        short8v a = *(const short8v*)(xnB + (size_t)(rb + lr) * DD + ks * 32 + lk);
        #pragma unroll
        for (int nf = 0; nf < 9; ++nf) {
            short8v b = *(const short8v*)(W3T + (size_t)(nf * 16 + lr) * DD + ks * 32 + lk);
            acc[nf] = __builtin_amdgcn_mfma_f32_16x16x32_bf16(b, a, acc[nf], 0, 0, 0);
        }
    }
    // acc[nf<8][r]: vo[m=lr][d=nf*16+g*4+r];  acc[8][r]: scores[m=lr][k2=g*4+r]

    #pragma unroll
    for (int r = 0; r < 4; ++r) {
        float sc = acc[8][r];
        float mx = sc;
        #pragma unroll
        for (int off = 1; off <= 8; off <<= 1) mx = fmaxf(mx, __shfl_xor(mx, off));
        float p = expf(sc - mx);
        float sm = p;
        #pragma unroll
        for (int off = 1; off <= 8; off <<= 1) sm += __shfl_xor(sm, off);
        sA[wv][lr * 16 + g * 4 + r] = p / sm;   // attn[m][k2]
    }
    #pragma unroll
    for (int nf = 0; nf < 8; ++nf) {
        float* dst = &sV[wv][lr * 130 + nf * 16 + g * 4];
        *(float2*)dst = make_float2(acc[nf][0], acc[nf][1]);
        *(float2*)(dst + 2) = make_float2(acc[nf][2], acc[nf][3]);
    }
    __syncthreads();

    float vo0[16], vo1[16];
    unsigned pe0[16], pe1[16];
    #pragma unroll
    for (int m = 0; m < 16; ++m) {
        float2 t = *(const float2*)&sV[wv][m * 130 + 2 * l];
        vo0[m] = t.x; vo1[m] = t.y;
        pe0[m] = *(const unsigned*)(Hpe + (size_t)(rb + m) * 256 + 2 * l);
        pe1[m] = *(const unsigned*)(Hpe + (size_t)(rb + m) * 256 + 128 + 2 * l);
    }
    const float A = -expf(A_log[0]);
    for (int k2 = 0; k2 < 16; ++k2) {
        float u0 = 0.f, u1 = 0.f, pd0 = 0.f, pd1 = 0.f, pb0 = 0.f, pb1 = 0.f;
        #pragma unroll
        for (int m = 0; m < 16; ++m) {
            float a = sA[wv][m * 16 + k2];
            u0 += a * vo0[m];       u1 += a * vo1[m];
            pd0 += a * blo(pe0[m]); pd1 += a * bhi(pe0[m]);
            pb0 += a * blo(pe1[m]); pb1 += a * bhi(pe1[m]);
        }
        float dt0 = fmaxf(pd0, 0.f) + log1pf(expf(-fabsf(pd0))) + DT_BIASf;
        float dt1 = fmaxf(pd1, 0.f) + log1pf(expf(-fabsf(pd1))) + DT_BIASf;
        float de0 = expf(dt0 * A), de1 = expf(dt1 * A);
        float db0 = dt0 * pb0 * u0, db1 = dt1 * pb1 * u1;
        size_t o = ((size_t)bt * KK + k2) * DD + 2 * l;
        *(float2*)(decayg + o) = make_float2(de0, de1);
        *(float2*)(dBug + o)   = make_float2(db0, db1);
    }
}

// ---------------------------------------------------------------------------
// scanA: per (b,k,chunk) local scan from 0 -> chunk aggregates P,S.
// ---------------------------------------------------------------------------
__global__ __launch_bounds__(128) void scanA_kernel(const float* decayg, const float* dBug,
                                                    float* __restrict__ Pc, float* __restrict__ Sc) {
    const int c = blockIdx.x & (CHUNKS - 1), bk = blockIdx.x >> 6;
    const int b = bk >> 4, k2 = bk & 15, d = threadIdx.x;
    const size_t base = (((size_t)b * TT + c * CLEN) * KK + k2) * DD + d;
    float P = 1.f, S = 0.f;
    #pragma unroll 4
    for (int j = 0; j < CLEN; ++j) {
        size_t idx = base + (size_t)j * (KK * DD);
        float de = decayg[idx], db = dBug[idx];
        P *= de;
        S = fmaf(de, S, db);
    }
    Pc[(size_t)blockIdx.x * DD + d] = P;
    Sc[(size_t)blockIdx.x * DD + d] = S;
}

// ---------------------------------------------------------------------------
// scanB: combine chunk aggregates -> per-chunk initial states. grid 64.
// ---------------------------------------------------------------------------
__global__ __launch_bounds__(128) void scanB_kernel(const float* __restrict__ Pc,
                                                    const float* __restrict__ Sc,
                                                    const float* __restrict__ slots_mu,
                                                    float* __restrict__ Hinit) {
    const int bk = blockIdx.x, k2 = bk & 15, d = threadIdx.x;
    float h = slots_mu[(size_t)k2 * DD + d];
    #pragma unroll 8
    for (int c = 0; c < CHUNKS; ++c) {
        size_t i = ((size_t)bk * CHUNKS + c) * DD + d;
        Hinit[i] = h;
        h = fmaf(Pc[i], h, Sc[i]);
    }
}

// ---------------------------------------------------------------------------
// scanC: local scan with correct init; write z_hat,z_all (overwriting the
// decay/dBu scratch living in d_out — read-before-write, same thread).
// ---------------------------------------------------------------------------
__global__ __launch_bounds__(128) void scanC_kernel(const float* decayg, const float* dBug,
                                                    const float* __restrict__ resg,
                                                    const float* __restrict__ Hinit,
                                                    float* outA, float* outB) {
    const int c = blockIdx.x & (CHUNKS - 1), bk = blockIdx.x >> 6;
    const int b = bk >> 4, k2 = bk & 15, d = threadIdx.x;
    const size_t base = (((size_t)b * TT + c * CLEN) * KK + k2) * DD + d;
    float h = Hinit[((size_t)bk * CHUNKS + c) * DD + d];
    #pragma unroll 4
    for (int j = 0; j < CLEN; ++j) {
        size_t idx = base + (size_t)j * (KK * DD);
        float de = decayg[idx], db = dBug[idx];
        h = fmaf(de, h, db);
        outA[idx] = h * resg[idx];
        outB[idx] = h;
    }
}

// ---------------------------------------------------------------------------
extern "C" void kernel_launch(void* const* d_in, const int* in_sizes, int n_in,
                              void* d_out, int out_size, void* d_ws, size_t ws_size,
                              hipStream_t stream) {
    const float* x        = (const float*)d_in[0];
    const float* W_in     = (const float*)d_in[1];
    const float* conv_w   = (const float*)d_in[2];
    const float* conv_b   = (const float*)d_in[3];
    const float* slots_mu = (const float*)d_in[4];
    const float* A_log    = (const float*)d_in[5];
    const float* ln_x_g   = (const float*)d_in[6];
    const float* ln_x_b   = (const float*)d_in[7];
    const float* ln_z_g   = (const float*)d_in[8];
    const float* ln_z_b   = (const float*)d_in[9];
    const float* Wq       = (const float*)d_in[10];
    const float* Wk       = (const float*)d_in[11];
    const float* Wv       = (const float*)d_in[12];
    const float* Wo       = (const float*)d_in[13];

    char* w = (char*)d_ws;
    auto give = [&](size_t bytes) -> char* {
        char* r = w; w += (bytes + 255) & ~(size_t)255; return r;
    };
    float* zbuf = (float*)give(256);
    unsigned short* WT  = (unsigned short*)give((size_t)512 * 256 * 2);
    unsigned short* W3T = (unsigned short*)give((size_t)144 * 128 * 2);
    unsigned short* Xb  = (unsigned short*)give((size_t)RTOT * 128 * 2);
    unsigned short* xnB = (unsigned short*)give((size_t)RTOT * 128 * 2);
    unsigned short* Hpe = (unsigned short*)give((size_t)RTOT * 256 * 2);
    float* resg  = (float*)give((size_t)RTOT * 128 * 4);
    float* Pc    = (float*)give((size_t)4096 * 128 * 4);
    float* Sc    = (float*)give((size_t)4096 * 128 * 4);
    float* Hinit = (float*)give((size_t)64 * CHUNKS * 128 * 4);

    float* decayg = (float*)d_out;              // d_out as scratch for decay
    float* dBug   = ((float*)d_out) + NTOT;     // and dBu

    wfold_kernel<<<dim3(512), dim3(256), 0, stream>>>(W_in, conv_w, WT);
    w3_kernel<<<dim3(144), dim3(128), 0, stream>>>(slots_mu, ln_z_g, ln_z_b, Wq, Wk, Wv, Wo, W3T);
    cvt_kernel<<<dim3(4096), dim3(256), 0, stream>>>(x, Xb, zbuf);
    gemm1_kernel<<<dim3(4096), dim3(256), 0, stream>>>(Xb, WT, zbuf, conv_b, ln_x_g, ln_x_b, xnB, Hpe, resg);
    gemm3f_kernel<<<dim3(2048), dim3(256), 0, stream>>>(xnB, W3T, Hpe, A_log, decayg, dBug);
    scanA_kernel<<<dim3(4096), dim3(128), 0, stream>>>(decayg, dBug, Pc, Sc);
    scanB_kernel<<<dim3(64), dim3(128), 0, stream>>>(Pc, Sc, slots_mu, Hinit);
    scanC_kernel<<<dim3(4096), dim3(128), 0, stream>>>(decayg, dBug, resg, Hinit, decayg, dBug);
}

// Round 5
// 467.733 us; speedup vs baseline: 3.0319x; 1.0756x over previous
//
#include <hip/hip_runtime.h>
#include <cstddef>

#define BN 4
#define TT 2048
#define MM 16
#define KK 16
#define DD 128
#define HO 384
#define RTOT (BN*TT*MM)                 // 131072 rows (b,t,m)
#define NTOT ((size_t)BN*TT*KK*DD)      // 16777216
#define LN_EPSf 1e-5f
#define DT_BIASf 1e-4f
#define CHUNKS 64
#define CLEN 32

typedef __attribute__((ext_vector_type(8))) short short8v;   // 8 x bf16 bits
typedef __attribute__((ext_vector_type(4))) float f32x4;

static __device__ __forceinline__ unsigned short f2b(float f) {
    union { float f; unsigned u; } x; x.f = f;
    unsigned r = (x.u + 0x7fffu + ((x.u >> 16) & 1u)) >> 16;   // RNE
    return (unsigned short)r;
}
static __device__ __forceinline__ unsigned pk2(float a, float b) {
    return (unsigned)f2b(a) | ((unsigned)f2b(b) << 16);
}
static __device__ __forceinline__ uint2 pack4(float a, float b, float c, float d) {
    uint2 r; r.x = pk2(a, b); r.y = pk2(c, d); return r;
}
static __device__ __forceinline__ short8v mk8(unsigned a, unsigned b, unsigned c, unsigned d) {
    union { unsigned u[4]; short8v v; } x;
    x.u[0] = a; x.u[1] = b; x.u[2] = c; x.u[3] = d;
    return x.v;
}
static __device__ __forceinline__ void gl_lds16(const void* g, void* l) {
    __builtin_amdgcn_global_load_lds(
        (const __attribute__((address_space(1))) void*)g,
        (__attribute__((address_space(3))) void*)l, 16, 0, 0);
}

// ---------------------------------------------------------------------------
// P1a: WT[n][k] (bf16, [512][256]) = conv folded through W_in (n<384) and
//      res-projection cols (n>=384). grid 512, block 256.
// ---------------------------------------------------------------------------
__global__ __launch_bounds__(256) void wfold_kernel(const float* __restrict__ W_in,
                                                    const float* __restrict__ conv_w,
                                                    unsigned short* __restrict__ WT) {
    const int n = blockIdx.x, tid = threadIdx.x;
    if (n < HO) {
        __shared__ float cw0[768], cw1[768];
        for (int i = tid; i < 768; i += 256) {
            cw0[i] = conv_w[(n * 768 + i) * 2 + 0];
            cw1[i] = conv_w[(n * 768 + i) * 2 + 1];
        }
        __syncthreads();
        const int k = tid, dd = k & 127;
        const float* cw = (k < 128) ? cw0 : cw1;   // k<128: x_prev tap; else x_cur tap
        const float* wr = W_in + (size_t)dd * 896;
        float acc = 0.f;
        #pragma unroll 8
        for (int i = 0; i < 768; ++i) acc += wr[i] * cw[i];
        WT[(size_t)n * 256 + k] = f2b(acc);
    } else {
        const int k = tid;
        float v = (k < 128) ? 0.f : W_in[(size_t)(k - 128) * 896 + 768 + (n - HO)];
        WT[(size_t)n * 256 + k] = f2b(v);
    }
}

// ---------------------------------------------------------------------------
// P1b: W3T ([144][128] bf16): rows 0..127 = Wvo^T (Wvo = Wv@Wo),
//      rows 128..143 = q' = LN_z(slots)@Wq@Wk^T * rsqrt(D). grid 144, block 128.
// ---------------------------------------------------------------------------
__global__ __launch_bounds__(128) void w3_kernel(const float* __restrict__ slots_mu,
                                                 const float* __restrict__ ln_z_g,
                                                 const float* __restrict__ ln_z_b,
                                                 const float* __restrict__ Wq,
                                                 const float* __restrict__ Wk,
                                                 const float* __restrict__ Wv,
                                                 const float* __restrict__ Wo,
                                                 unsigned short* __restrict__ W3T) {
    const int n = blockIdx.x, tid = threadIdx.x;
    if (n < 128) {
        __shared__ float wo[128];
        wo[tid] = Wo[(size_t)tid * 128 + n];
        __syncthreads();
        const float* wv = Wv + (size_t)tid * 128;
        float acc = 0.f;
        #pragma unroll 8
        for (int c = 0; c < 128; ++c) acc += wv[c] * wo[c];
        W3T[(size_t)n * 128 + tid] = f2b(acc);
    } else {
        const int k2 = n - 128;
        __shared__ float zn[128], qv[128];
        __shared__ float red[4];
        float v = slots_mu[(size_t)k2 * 128 + tid];
        float s = v, ss = v * v;
        #pragma unroll
        for (int o = 32; o; o >>= 1) { s += __shfl_xor(s, o); ss += __shfl_xor(ss, o); }
        if ((tid & 63) == 0) { red[(tid >> 6) * 2] = s; red[(tid >> 6) * 2 + 1] = ss; }
        __syncthreads();
        float S = red[0] + red[2], SS = red[1] + red[3];
        float mu = S * (1.f / 128.f), var = SS * (1.f / 128.f) - mu * mu;
        float rs = rsqrtf(var + LN_EPSf);
        zn[tid] = (v - mu) * rs * ln_z_g[tid] + ln_z_b[tid];
        __syncthreads();
        float a = 0.f;
        for (int dd2 = 0; dd2 < 128; ++dd2) a += zn[dd2] * Wq[(size_t)dd2 * 128 + tid];
        qv[tid] = a;
        __syncthreads();
        float qp = 0.f;
        for (int c = 0; c < 128; ++c) qp += qv[c] * Wk[(size_t)tid * 128 + c];
        W3T[(size_t)n * 128 + tid] = f2b(qp * 0.08838834764831845f);
    }
}

// ---------------------------------------------------------------------------
// P2: x (fp32) -> Xb (bf16) + zero the 256-B zbuf. grid 4096, block 256.
// ---------------------------------------------------------------------------
__global__ __launch_bounds__(256) void cvt_kernel(const float* __restrict__ x,
                                                  unsigned short* __restrict__ Xb,
                                                  float* __restrict__ zbuf) {
    if (blockIdx.x == 0 && threadIdx.x < 64) zbuf[threadIdx.x] = 0.f;
    const size_t t0 = (size_t)blockIdx.x * 256 + threadIdx.x;
    #pragma unroll
    for (int it = 0; it < 4; ++it) {
        size_t i = t0 + (size_t)it * 1048576;
        float4 v = ((const float4*)x)[i];
        union { unsigned short s[4]; unsigned long long ll; } o;
        o.s[0] = f2b(v.x); o.s[1] = f2b(v.y); o.s[2] = f2b(v.z); o.s[3] = f2b(v.w);
        ((unsigned long long*)Xb)[i] = o.ll;
    }
}

// ---------------------------------------------------------------------------
// GEMM1 (m97-style): [131072][256] (im2col of Xb) @ WT^T.
// 128x128 tile, BK=64, LDS-staged via global_load_lds(16B), XOR-swizzled
// chunks (chunk ^= row&7) on BOTH stage-source and ds_read.
// Swapped-operand MFMA: lane&15 = x-row, regs = 4 consecutive cols.
//  ct=0: +conv_b -> LN -> xnB bf16
//  ct=1,2: +conv_b -> peT bf16 (TRANSPOSED per-bt: peT[bt][p][m])
//  ct=3: silu -> resg fp32
// grid 4096 (ct=bid&3, rt=bid>>2), block 256.
// ---------------------------------------------------------------------------
__global__ __launch_bounds__(256) void gemm1_kernel(const unsigned short* __restrict__ Xb,
                                                    const unsigned short* __restrict__ WT,
                                                    const float* __restrict__ zbuf,
                                                    const float* __restrict__ conv_b,
                                                    const float* __restrict__ ln_x_g,
                                                    const float* __restrict__ ln_x_b,
                                                    unsigned short* __restrict__ xnB,
                                                    unsigned short* __restrict__ peT,
                                                    float* __restrict__ resg) {
    __shared__ unsigned short Asm[128 * 64];   // 16 KB, [row][64k], swizzled 16B chunks
    __shared__ unsigned short Bsm[128 * 64];   // 16 KB, [n][64k], swizzled

    const int bid = blockIdx.x;
    const int ct = bid & 3, rt = bid >> 2;
    const int tid = threadIdx.x;
    const int wv = tid >> 6, l = tid & 63;
    const int lr = l & 15, g = l >> 4;
    const int rowbase = rt * 128;
    const int colbase = ct * 128;

    const char* XbB = (const char*)Xb;
    const char* WTB = (const char*)WT;
    char* AsmB = (char*)Asm;
    char* BsmB = (char*)Bsm;

    f32x4 acc[2][8];
    #pragma unroll
    for (int i = 0; i < 2; ++i)
        #pragma unroll
        for (int j = 0; j < 8; ++j) acc[i][j] = (f32x4)0.f;

    const bool edge = (rt & 255) == 0;          // tile contains t=0 rows (0..15)

    #pragma unroll
    for (int ks = 0; ks < 4; ++ks) {
        // ---- stage A and B tiles (each wave: 4+4 issues of 1KB) ----
        #pragma unroll
        for (int j = 0; j < 4; ++j) {
            const int seg = wv * 4 + j;
            const int row = seg * 8 + (l >> 3);      // 0..127
            const int chunk = l & 7;
            const int gch = chunk ^ (row & 7);
            {
                const int grow = rowbase + row + (ks < 2 ? -16 : 0);
                const bool ok = (ks >= 2) || !edge || (row >= 16);
                const char* src = ok ? (XbB + ((size_t)grow * 256 + (ks & 1) * 128 + gch * 16))
                                     : (const char*)zbuf;
                gl_lds16(src, AsmB + seg * 1024);
            }
            {
                const int n = colbase + row;
                gl_lds16(WTB + ((size_t)n * 512 + ks * 128 + gch * 16), BsmB + seg * 1024);
            }
        }
        __syncthreads();

        // ---- compute: 2 kb x (2 a-frags + 8 b-frags + 16 MFMA) per wave ----
        #pragma unroll
        for (int kb = 0; kb < 2; ++kb) {
            short8v a[2], b[8];
            #pragma unroll
            for (int mf = 0; mf < 2; ++mf) {
                const int arow = wv * 32 + mf * 16 + lr;
                const int aoff = arow * 128 + (((kb * 4 + g) ^ (arow & 7)) * 16);
                a[mf] = *(const short8v*)(AsmB + aoff);
            }
            #pragma unroll
            for (int nf = 0; nf < 8; ++nf) {
                const int brow = nf * 16 + lr;
                const int boff = brow * 128 + (((kb * 4 + g) ^ (brow & 7)) * 16);
                b[nf] = *(const short8v*)(BsmB + boff);
            }
            #pragma unroll
            for (int mf = 0; mf < 2; ++mf)
                #pragma unroll
                for (int nf = 0; nf < 8; ++nf)
                    acc[mf][nf] = __builtin_amdgcn_mfma_f32_16x16x32_bf16(b[nf], a[mf], acc[mf][nf], 0, 0, 0);
        }
        __syncthreads();
    }
    // lane holds: row = rowbase + wv*32 + mf*16 + lr; cols = colbase + nf*16 + g*4 + r

    if (ct == 0) {
        f32x4 cb[8];
        #pragma unroll
        for (int nf = 0; nf < 8; ++nf) cb[nf] = *(const f32x4*)(conv_b + nf * 16 + g * 4);
        #pragma unroll
        for (int mf = 0; mf < 2; ++mf) {
            float s = 0.f, ss = 0.f;
            #pragma unroll
            for (int nf = 0; nf < 8; ++nf)
                #pragma unroll
                for (int r = 0; r < 4; ++r) {
                    float v = acc[mf][nf][r] + cb[nf][r];
                    acc[mf][nf][r] = v;
                    s += v; ss += v * v;
                }
            s += __shfl_xor(s, 16);  s += __shfl_xor(s, 32);
            ss += __shfl_xor(ss, 16); ss += __shfl_xor(ss, 32);
            float mu = s * (1.f / 128.f);
            float var = ss * (1.f / 128.f) - mu * mu;
            float rs = rsqrtf(var + LN_EPSf);
            const int row = rowbase + wv * 32 + mf * 16 + lr;
            #pragma unroll
            for (int nf = 0; nf < 8; ++nf) {
                f32x4 gv = *(const f32x4*)(ln_x_g + nf * 16 + g * 4);
                f32x4 bv = *(const f32x4*)(ln_x_b + nf * 16 + g * 4);
                float o0 = (acc[mf][nf][0] - mu) * rs * gv[0] + bv[0];
                float o1 = (acc[mf][nf][1] - mu) * rs * gv[1] + bv[1];
                float o2 = (acc[mf][nf][2] - mu) * rs * gv[2] + bv[2];
                float o3 = (acc[mf][nf][3] - mu) * rs * gv[3] + bv[3];
                *(uint2*)(xnB + (size_t)row * DD + nf * 16 + g * 4) = pack4(o0, o1, o2, o3);
            }
        }
    } else if (ct < 3) {
        // peT[bt][p][m]: p = colbase-128 + nf*16 + g*4 + r, m = lr
        f32x4 cb[8];
        #pragma unroll
        for (int nf = 0; nf < 8; ++nf) cb[nf] = *(const f32x4*)(conv_b + colbase + nf * 16 + g * 4);
        #pragma unroll
        for (int mf = 0; mf < 2; ++mf) {
            const int btq = rt * 8 + wv * 2 + mf;
            unsigned short* dst = peT + (size_t)btq * 4096 + lr;
            const int pbase = (colbase - 128) + g * 4;
            #pragma unroll
            for (int nf = 0; nf < 8; ++nf) {
                #pragma unroll
                for (int r = 0; r < 4; ++r) {
                    dst[(size_t)(pbase + nf * 16 + r) * 16] = f2b(acc[mf][nf][r] + cb[nf][r]);
                }
            }
        }
    } else {
        #pragma unroll
        for (int mf = 0; mf < 2; ++mf) {
            const int row = rowbase + wv * 32 + mf * 16 + lr;
            #pragma unroll
            for (int nf = 0; nf < 8; ++nf) {
                f32x4 o;
                #pragma unroll
                for (int r = 0; r < 4; ++r) {
                    float v = acc[mf][nf][r];
                    o[r] = v / (1.f + __expf(-v));
                }
                *(f32x4*)(resg + (size_t)row * DD + nf * 16 + g * 4) = o;
            }
        }
    }
}

// ---------------------------------------------------------------------------
// GEMM3F (all-MFMA): wave = one (b,t). No LDS.
//  1) unswapped GEMM: acc[nf] = [vo|scores][m=(l>>4)*4+r][col=nf*16+(l&15)]
//  2) softmax over m via reg-reduce + shfl_xor(16,32)
//  3) attn/vo repacked in-register (bf16 pack + 4 shuffles) into MFMA frags
//  4) u = attn@vo (8 mfma), pe_r = attn@pe (16 mfma, B-frags from peT 16B loads)
//  5) dt/decay/dBu -> d_out scratch.
// grid 2048, block 256 (4 waves, 4 bt).
// ---------------------------------------------------------------------------
__global__ __launch_bounds__(256) void gemm3f_kernel(const unsigned short* __restrict__ xnB,
                                                     const unsigned short* __restrict__ W3T,
                                                     const unsigned short* __restrict__ peT,
                                                     const float* __restrict__ A_log,
                                                     float* __restrict__ decayg,
                                                     float* __restrict__ dBug) {
    const int tid = threadIdx.x, wv = tid >> 6, l = tid & 63;
    const int lr = l & 15, g = l >> 4;
    const int bt = blockIdx.x * 4 + wv;
    const int rb = bt * 16;

    // ---- first GEMM (unswapped): rows = m, cols = [vo 0..127 | scores 128..143]
    f32x4 acc[9];
    #pragma unroll
    for (int j = 0; j < 9; ++j) acc[j] = (f32x4)0.f;
    #pragma unroll
    for (int ks = 0; ks < 4; ++ks) {
        short8v a = *(const short8v*)(xnB + (size_t)(rb + lr) * DD + ks * 32 + g * 8);
        #pragma unroll
        for (int nf = 0; nf < 9; ++nf) {
            short8v b = *(const short8v*)(W3T + (size_t)(nf * 16 + lr) * DD + ks * 32 + g * 8);
            acc[nf] = __builtin_amdgcn_mfma_f32_16x16x32_bf16(a, b, acc[nf], 0, 0, 0);
        }
    }
    // acc[nf][r] = out[m = g*4+r][col = nf*16+lr];  acc[8] = scores[m][k2=lr]

    // ---- softmax over m (per k2 = lr) ----
    float mx = fmaxf(fmaxf(acc[8][0], acc[8][1]), fmaxf(acc[8][2], acc[8][3]));
    mx = fmaxf(mx, __shfl_xor(mx, 16));
    mx = fmaxf(mx, __shfl_xor(mx, 32));
    float p0 = __expf(acc[8][0] - mx), p1 = __expf(acc[8][1] - mx);
    float p2 = __expf(acc[8][2] - mx), p3 = __expf(acc[8][3] - mx);
    float sm = p0 + p1 + p2 + p3;
    sm += __shfl_xor(sm, 16);
    sm += __shfl_xor(sm, 32);
    const float inv = 1.f / sm;

    // ---- attn A-frag: lane l holds attn[k2=lr][m=8g+j], zero for g>=2 ----
    const int srcA = lr + ((g & 1) << 5), srcB = srcA + 16;
    unsigned PA0 = pk2(p0 * inv, p1 * inv);
    unsigned PA1 = pk2(p2 * inv, p3 * inv);
    unsigned A0 = __shfl(PA0, srcA), A1 = __shfl(PA1, srcA);
    unsigned A2 = __shfl(PA0, srcB), A3 = __shfl(PA1, srcB);
    if (g >= 2) { A0 = 0; A1 = 0; A2 = 0; A3 = 0; }
    const short8v attnA = mk8(A0, A1, A2, A3);

    // ---- u = attn @ vo : vo B-frags via in-register repack ----
    f32x4 pvo[8];
    #pragma unroll
    for (int nf = 0; nf < 8; ++nf) {
        unsigned Q0 = pk2(acc[nf][0], acc[nf][1]);
        unsigned Q1 = pk2(acc[nf][2], acc[nf][3]);
        short8v bf = mk8(__shfl(Q0, srcA), __shfl(Q1, srcA), __shfl(Q0, srcB), __shfl(Q1, srcB));
        pvo[nf] = __builtin_amdgcn_mfma_f32_16x16x32_bf16(attnA, bf, (f32x4)0.f, 0, 0, 0);
    }

    // ---- pe_r = attn @ pe : B-frags straight from peT ----
    f32x4 ppe[16];
    const unsigned short* pbase = peT + (size_t)bt * 4096 + g * 8;
    #pragma unroll
    for (int nf = 0; nf < 16; ++nf) {
        short8v bf = *(const short8v*)(pbase + (nf * 16 + lr) * 16);
        ppe[nf] = __builtin_amdgcn_mfma_f32_16x16x32_bf16(attnA, bf, (f32x4)0.f, 0, 0, 0);
    }
    // pvo[nf][r] = u[k2=g*4+r][d=nf*16+lr]; ppe: nf<8 -> dt-part, nf>=8 -> Bp

    const float A = -__expf(A_log[0]);
    #pragma unroll
    for (int nf = 0; nf < 8; ++nf) {
        const int d = nf * 16 + lr;
        #pragma unroll
        for (int r = 0; r < 4; ++r) {
            const int k2 = g * 4 + r;
            float pd = ppe[nf][r];
            float pb = ppe[nf + 8][r];
            float u  = pvo[nf][r];
            float dt = fmaxf(pd, 0.f) + __logf(1.f + __expf(-fabsf(pd))) + DT_BIASf;
            size_t o = (size_t)bt * 2048 + (size_t)k2 * 128 + d;
            decayg[o] = __expf(dt * A);
            dBug[o]   = dt * pb * u;
        }
    }
}

// ---------------------------------------------------------------------------
// scanA: per (b,k,chunk) local scan from 0 -> chunk aggregates P,S.
// ---------------------------------------------------------------------------
__global__ __launch_bounds__(128) void scanA_kernel(const float* decayg, const float* dBug,
                                                    float* __restrict__ Pc, float* __restrict__ Sc) {
    const int c = blockIdx.x & (CHUNKS - 1), bk = blockIdx.x >> 6;
    const int b = bk >> 4, k2 = bk & 15, d = threadIdx.x;
    const size_t base = (((size_t)b * TT + c * CLEN) * KK + k2) * DD + d;
    float P = 1.f, S = 0.f;
    #pragma unroll 4
    for (int j = 0; j < CLEN; ++j) {
        size_t idx = base + (size_t)j * (KK * DD);
        float de = decayg[idx], db = dBug[idx];
        P *= de;
        S = fmaf(de, S, db);
    }
    Pc[(size_t)blockIdx.x * DD + d] = P;
    Sc[(size_t)blockIdx.x * DD + d] = S;
}

// ---------------------------------------------------------------------------
// scanB: combine chunk aggregates -> per-chunk initial states. grid 64.
// ---------------------------------------------------------------------------
__global__ __launch_bounds__(128) void scanB_kernel(const float* __restrict__ Pc,
                                                    const float* __restrict__ Sc,
                                                    const float* __restrict__ slots_mu,
                                                    float* __restrict__ Hinit) {
    const int bk = blockIdx.x, k2 = bk & 15, d = threadIdx.x;
    float h = slots_mu[(size_t)k2 * DD + d];
    #pragma unroll 8
    for (int c = 0; c < CHUNKS; ++c) {
        size_t i = ((size_t)bk * CHUNKS + c) * DD + d;
        Hinit[i] = h;
        h = fmaf(Pc[i], h, Sc[i]);
    }
}

// ---------------------------------------------------------------------------
// scanC: local scan with correct init; write z_hat,z_all (overwriting the
// decay/dBu scratch living in d_out — read-before-write, same thread).
// ---------------------------------------------------------------------------
__global__ __launch_bounds__(128) void scanC_kernel(const float* decayg, const float* dBug,
                                                    const float* __restrict__ resg,
                                                    const float* __restrict__ Hinit,
                                                    float* outA, float* outB) {
    const int c = blockIdx.x & (CHUNKS - 1), bk = blockIdx.x >> 6;
    const int b = bk >> 4, k2 = bk & 15, d = threadIdx.x;
    const size_t base = (((size_t)b * TT + c * CLEN) * KK + k2) * DD + d;
    float h = Hinit[((size_t)bk * CHUNKS + c) * DD + d];
    #pragma unroll 4
    for (int j = 0; j < CLEN; ++j) {
        size_t idx = base + (size_t)j * (KK * DD);
        float de = decayg[idx], db = dBug[idx];
        h = fmaf(de, h, db);
        outA[idx] = h * resg[idx];
        outB[idx] = h;
    }
}

// ---------------------------------------------------------------------------
extern "C" void kernel_launch(void* const* d_in, const int* in_sizes, int n_in,
                              void* d_out, int out_size, void* d_ws, size_t ws_size,
                              hipStream_t stream) {
    const float* x        = (const float*)d_in[0];
    const float* W_in     = (const float*)d_in[1];
    const float* conv_w   = (const float*)d_in[2];
    const float* conv_b   = (const float*)d_in[3];
    const float* slots_mu = (const float*)d_in[4];
    const float* A_log    = (const float*)d_in[5];
    const float* ln_x_g   = (const float*)d_in[6];
    const float* ln_x_b   = (const float*)d_in[7];
    const float* ln_z_g   = (const float*)d_in[8];
    const float* ln_z_b   = (const float*)d_in[9];
    const float* Wq       = (const float*)d_in[10];
    const float* Wk       = (const float*)d_in[11];
    const float* Wv       = (const float*)d_in[12];
    const float* Wo       = (const float*)d_in[13];

    char* w = (char*)d_ws;
    auto give = [&](size_t bytes) -> char* {
        char* r = w; w += (bytes + 255) & ~(size_t)255; return r;
    };
    float* zbuf = (float*)give(256);
    unsigned short* WT  = (unsigned short*)give((size_t)512 * 256 * 2);
    unsigned short* W3T = (unsigned short*)give((size_t)144 * 128 * 2);
    unsigned short* Xb  = (unsigned short*)give((size_t)RTOT * 128 * 2);
    unsigned short* xnB = (unsigned short*)give((size_t)RTOT * 128 * 2);
    unsigned short* peT = (unsigned short*)give((size_t)RTOT * 256 * 2 + 256);  // [bt][256][16]
    float* resg  = (float*)give((size_t)RTOT * 128 * 4);
    float* Pc    = (float*)give((size_t)4096 * 128 * 4);
    float* Sc    = (float*)give((size_t)4096 * 128 * 4);
    float* Hinit = (float*)give((size_t)64 * CHUNKS * 128 * 4);

    float* decayg = (float*)d_out;              // d_out as scratch for decay
    float* dBug   = ((float*)d_out) + NTOT;     // and dBu

    wfold_kernel<<<dim3(512), dim3(256), 0, stream>>>(W_in, conv_w, WT);
    w3_kernel<<<dim3(144), dim3(128), 0, stream>>>(slots_mu, ln_z_g, ln_z_b, Wq, Wk, Wv, Wo, W3T);
    cvt_kernel<<<dim3(4096), dim3(256), 0, stream>>>(x, Xb, zbuf);
    gemm1_kernel<<<dim3(4096), dim3(256), 0, stream>>>(Xb, WT, zbuf, conv_b, ln_x_g, ln_x_b, xnB, peT, resg);
    gemm3f_kernel<<<dim3(2048), dim3(256), 0, stream>>>(xnB, W3T, peT, A_log, decayg, dBug);
    scanA_kernel<<<dim3(4096), dim3(128), 0, stream>>>(decayg, dBug, Pc, Sc);
    scanB_kernel<<<dim3(64), dim3(128), 0, stream>>>(Pc, Sc, slots_mu, Hinit);
    scanC_kernel<<<dim3(4096), dim3(128), 0, stream>>>(decayg, dBug, resg, Hinit, decayg, dBug);
}